// Round 12
// baseline (2072.176 us; speedup 1.0000x reference)
//
#include <hip/hip_runtime.h>

// GPT-2 small forward: B=2, S=1024, D=768, H=12, HD=64, L=12, DFF=3072, V=50257
#define BB 2
#define SS 1024
#define DM 768
#define NH 12
#define HDIM 64
#define NL 12
#define DFFN 3072
#define VOC 50257
#define ROWS (BB * SS)   // 2048
#define MT (ROWS / 128)  // 16 M-tiles for 128-row GEMMs

typedef __attribute__((ext_vector_type(4))) float f32x4;
typedef __attribute__((ext_vector_type(8))) short short8;
typedef __attribute__((ext_vector_type(4))) short short4v;
typedef unsigned short ushort;

__device__ __forceinline__ ushort f2bf(float f) {
  union { float f; unsigned int u; } x; x.f = f;
  unsigned int u = x.u;
  unsigned int r = (u + 0x7FFFu + ((u >> 16) & 1u)) >> 16;
  return (ushort)r;
}

// ---------------- embedding ----------------
__global__ __launch_bounds__(256) void embed_k(const int* __restrict__ ids,
    const float* __restrict__ wte, const float* __restrict__ wpe,
    float* __restrict__ h) {
  const int row = blockIdx.x;
  const int s = row & (SS - 1);
  const int tid = threadIdx.x;
  const int id = ids[row];
  const size_t wbase = (size_t)id * DM;
  const size_t pbase = (size_t)s * DM;
  const size_t obase = (size_t)row * DM;
  h[obase + tid]       = wte[wbase + tid]       + wpe[pbase + tid];
  h[obase + tid + 256] = wte[wbase + tid + 256] + wpe[pbase + tid + 256];
  h[obase + tid + 512] = wte[wbase + tid + 512] + wpe[pbase + tid + 512];
}

// ---------------- fp32 -> bf16 bulk convert ----------------
__global__ __launch_bounds__(256) void f2b_k(const float* __restrict__ in,
                                             ushort* __restrict__ out, int n4) {
  for (int i = blockIdx.x * 256 + threadIdx.x; i < n4; i += gridDim.x * 256) {
    f32x4 v = ((const f32x4*)in)[i];
    short4v s;
    s[0] = f2bf(v[0]); s[1] = f2bf(v[1]); s[2] = f2bf(v[2]); s[3] = f2bf(v[3]);
    ((short4v*)out)[i] = s;
  }
}

// ---------------- layernorm: one WAVE per row, shuffle-only ----------------
template <int OB>
__global__ __launch_bounds__(256) void layernorm_t(const float* __restrict__ x,
    const float* __restrict__ g, const float* __restrict__ b, void* __restrict__ y) {
  const int tid = threadIdx.x;
  const int lane = tid & 63;
  const int wave = tid >> 6;
  const int row = blockIdx.x * 4 + wave;
  const size_t base = (size_t)row * DM;

  f32x4 v[3];
  float sum = 0.f;
#pragma unroll
  for (int k = 0; k < 3; k++) {
    v[k] = *(const f32x4*)&x[base + k * 256 + lane * 4];
    sum += v[k][0] + v[k][1] + v[k][2] + v[k][3];
  }
#pragma unroll
  for (int off = 32; off >= 1; off >>= 1) sum += __shfl_xor(sum, off);
  const float mu = sum * (1.0f / DM);

  float var = 0.f;
#pragma unroll
  for (int k = 0; k < 3; k++)
#pragma unroll
    for (int i = 0; i < 4; i++) {
      const float d = v[k][i] - mu;
      var += d * d;
    }
#pragma unroll
  for (int off = 32; off >= 1; off >>= 1) var += __shfl_xor(var, off);
  const float rstd = rsqrtf(var * (1.0f / DM) + 1e-5f);

#pragma unroll
  for (int k = 0; k < 3; k++) {
    const int col = k * 256 + lane * 4;
    f32x4 gv = *(const f32x4*)&g[col];
    f32x4 bv = *(const f32x4*)&b[col];
    if (OB) {
      short4v o;
#pragma unroll
      for (int i = 0; i < 4; i++)
        o[i] = f2bf((v[k][i] - mu) * rstd * gv[i] + bv[i]);
      *(short4v*)&((ushort*)y)[base + col] = o;
    } else {
      f32x4 o;
#pragma unroll
      for (int i = 0; i < 4; i++)
        o[i] = (v[k][i] - mu) * rstd * gv[i] + bv[i];
      *(f32x4*)&((float*)y)[base + col] = o;
    }
  }
}

// -------- async stage (4 waves), T2 pre-swizzled source, linear LDS dest ---
template <int ROUNDS>
__device__ __forceinline__ void stage_sw(const ushort* __restrict__ g, int ldg,
                                         ushort* lds, int wave, int lane,
                                         int rowmax) {
#pragma unroll
  for (int r = 0; r < ROUNDS; r++) {
    const int chunk = (r * 4 + wave) * 64 + lane;
    const int nrow = chunk >> 3;
    const int cs = (chunk & 7) ^ (nrow & 7);
    const int row = nrow > rowmax ? rowmax : nrow;
    const ushort* ga = g + (size_t)row * ldg + cs * 8;
    ushort* la = lds + (r * 4 + wave) * 512;
    __builtin_amdgcn_global_load_lds(
        (const __attribute__((address_space(1))) unsigned int*)ga,
        (__attribute__((address_space(3))) unsigned int*)la, 16, 0, 0);
  }
}

// -------- half-tile stage for 512-thread blocks: 128x64 bf16, 2 loads/thread
__device__ __forceinline__ void stage_half(const ushort* __restrict__ g, int ldg,
                                           ushort* lds, int rbase, int rowmax,
                                           int tid) {
#pragma unroll
  for (int i = 0; i < 2; i++) {
    const int c = i * 512 + tid;          // chunk id 0..1023
    const int nrow = c >> 3;              // local row 0..127
    const int cs = (c & 7) ^ (nrow & 7);  // swizzled source column chunk
    int row = rbase + nrow;
    if (row > rowmax) row = rowmax;
    const ushort* ga = g + (size_t)row * ldg + cs * 8;
    ushort* la = lds + (size_t)(i * 512 + (tid & ~63)) * 8;  // wave-uniform
    __builtin_amdgcn_global_load_lds(
        (const __attribute__((address_space(1))) unsigned int*)ga,
        (__attribute__((address_space(3))) unsigned int*)la, 16, 0, 0);
  }
}

// ---------------- logits GEMM: 256x256, 8 waves, fine-phased (4 phases/tile)
// Per phase: {stage half-tiles | 12 ds_read} -> barrier -> lgkmcnt(0) ->
// setprio(1) 16 MFMA setprio(0) -> barrier. Boundary: vmcnt(0)+barrier.
__global__ __launch_bounds__(512, 2) void gemm_256(const ushort* __restrict__ A,
    const ushort* __restrict__ Bw, float* __restrict__ Cout, int N, int K) {
  constexpr int TSZ = 256 * 64;                    // ushorts per full tile
  __shared__ __align__(16) ushort smem[4 * TSZ];   // 128 KB
  ushort* As = smem;            // [2][TSZ]
  ushort* Bs = smem + 2 * TSZ;  // [2][TSZ]

  const int tid = threadIdx.x;
  const int lane = tid & 63;
  const int la = lane & 15;
  const int hi = lane >> 4;
  const int swz = (la & 7) << 3;
  const int wave = tid >> 6;    // 0..7
  const int wr2 = wave >> 2;    // row half
  const int wc2 = wave & 3;     // col quarter

  const int nwg = gridDim.x;
  int bid = blockIdx.x;
  {
    const int q = nwg >> 3, r = nwg & 7;
    const int xcd = bid & 7, idx = bid >> 3;
    bid = (xcd < r ? xcd * (q + 1) : r * (q + 1) + (xcd - r) * q) + idx;
  }
  const int m0 = (bid & 7) * 256;
  const int n0 = (bid >> 3) * 256;
  const int brmax = min(N - n0 - 1, 255);

  f32x4 acc[8][4];
#pragma unroll
  for (int i = 0; i < 8; i++)
#pragma unroll
    for (int j = 0; j < 4; j++) acc[i][j] = (f32x4){0.f, 0.f, 0.f, 0.f};

  const ushort* Ag = A + (size_t)m0 * K;
  const ushort* Bg = Bw + (size_t)n0 * K;
  const int nt = K >> 6;            // 12
  const int s0 = bid % nt;

  // prologue: stage tile 0 (slab s0), all four halves
  {
    const ushort* Ags = Ag + s0 * 64;
    const ushort* Bgs = Bg + s0 * 64;
    stage_half(Ags, K, As, 0, 255, tid);
    stage_half(Ags, K, As + 8192, 128, 255, tid);
    stage_half(Bgs, K, Bs, 0, brmax, tid);
    stage_half(Bgs, K, Bs + 8192, 128, brmax, tid);
  }
  asm volatile("s_waitcnt vmcnt(0)" ::: "memory");
  __builtin_amdgcn_s_barrier();
  __builtin_amdgcn_sched_barrier(0);

  for (int t = 0; t < nt; t++) {
    const int cb = t & 1, nb = cb ^ 1;
    const ushort* Abase = As + cb * TSZ + (wr2 * 128 + la) * 64;
    const ushort* Bbase = Bs + cb * TSZ + (wc2 * 64 + la) * 64;

#pragma unroll
    for (int q = 0; q < 4; q++) {
      // stage tile t+1: A halves at q=0, B halves at q=1
      if (t + 1 < nt) {
        int sn = t + 1 + s0; if (sn >= nt) sn -= nt;
        if (q == 0) {
          stage_half(Ag + sn * 64, K, As + nb * TSZ, 0, 255, tid);
          stage_half(Ag + sn * 64, K, As + nb * TSZ + 8192, 128, 255, tid);
        } else if (q == 1) {
          stage_half(Bg + sn * 64, K, Bs + nb * TSZ, 0, brmax, tid);
          stage_half(Bg + sn * 64, K, Bs + nb * TSZ + 8192, 128, brmax, tid);
        }
      }
      const int mq = q >> 1, nq = q & 1;
      short8 a[2][4], b[2][2];
#pragma unroll
      for (int ks = 0; ks < 2; ks++) {
        const int co = (ks * 32 + hi * 8) ^ swz;
#pragma unroll
        for (int i = 0; i < 4; i++)
          a[ks][i] = *(const short8*)(Abase + (mq * 64 + i * 16) * 64 + co);
#pragma unroll
        for (int j = 0; j < 2; j++)
          b[ks][j] = *(const short8*)(Bbase + (nq * 32 + j * 16) * 64 + co);
      }
      __builtin_amdgcn_s_barrier();
      asm volatile("s_waitcnt lgkmcnt(0)" ::: "memory");
      __builtin_amdgcn_sched_barrier(0);
      __builtin_amdgcn_s_setprio(1);
#pragma unroll
      for (int ks = 0; ks < 2; ks++)
#pragma unroll
        for (int i = 0; i < 4; i++)
#pragma unroll
          for (int j = 0; j < 2; j++)
            acc[mq * 4 + i][nq * 2 + j] = __builtin_amdgcn_mfma_f32_16x16x32_bf16(
                a[ks][i], b[ks][j], acc[mq * 4 + i][nq * 2 + j], 0, 0, 0);
      __builtin_amdgcn_s_setprio(0);
      __builtin_amdgcn_sched_barrier(0);
      __builtin_amdgcn_s_barrier();
    }
    // tile boundary: all of tile t+1's halves must have landed for all waves
    if (t + 1 < nt) {
      asm volatile("s_waitcnt vmcnt(0)" ::: "memory");
      __builtin_amdgcn_s_barrier();
      __builtin_amdgcn_sched_barrier(0);
    }
  }

  // ---- 4-pass column-quarter fp32 LDS-transpose epilogue ----
  float* L = (float*)smem;   // [256][68]
#pragma unroll
  for (int p = 0; p < 4; p++) {
    if (wc2 == p) {
#pragma unroll
      for (int mi = 0; mi < 8; mi++)
#pragma unroll
        for (int ni = 0; ni < 4; ni++)
#pragma unroll
          for (int j = 0; j < 4; j++) {
            const int row = wr2 * 128 + mi * 16 + 4 * hi + j;
            const int col = ni * 16 + la;
            L[row * 68 + col] = acc[mi][ni][j];
          }
    }
    __syncthreads();
#pragma unroll
    for (int it = 0; it < 32; it++) {
      const int flat = it * 512 + tid;       // 0..16383
      const int row = flat >> 6, col = flat & 63;
      const int gc = n0 + p * 64 + col;
      if (gc < N)
        Cout[(size_t)(m0 + row) * N + gc] = L[row * 68 + col];
    }
    __syncthreads();
  }
}

// -------- layer GEMM: MROWS x 64 tile, 3-buffer depth-2, K-stagger ---------
template <int EPI, int OUTBF, int MR>
__global__ __launch_bounds__(256) void gemm_p3(const ushort* __restrict__ A,
    const ushort* __restrict__ Bw, const float* __restrict__ bias,
    const float* __restrict__ res, void* __restrict__ Cout, int N, int K) {
  constexpr int MROWS = MR * 32;
  constexpr int MTILES = ROWS / MROWS;
  constexpr int ASZ = MROWS * 64;
  constexpr int BSZ = 64 * 64;
  __shared__ __align__(16) ushort smem[3 * ASZ + 3 * BSZ];
  ushort* As = smem;
  ushort* Bs = smem + 3 * ASZ;

  const int tid = threadIdx.x;
  const int lane = tid & 63;
  const int wave = tid >> 6;
  const int la = lane & 15;
  const int hi = lane >> 4;
  const int swz = (la & 7) << 3;

  const int nwg = gridDim.x;
  int bid = blockIdx.x;
  {
    const int q = nwg >> 3, r = nwg & 7;
    const int xcd = bid & 7, idx = bid >> 3;
    bid = (xcd < r ? xcd * (q + 1) : r * (q + 1) + (xcd - r) * q) + idx;
  }
  const int m0 = (bid % MTILES) * MROWS;
  const int n0 = (bid / MTILES) * 64;

  const int wr = (wave >> 1) * (MROWS / 2);
  const int wc = (wave & 1) * 32;

  f32x4 acc[MR][2];
#pragma unroll
  for (int i = 0; i < MR; i++)
#pragma unroll
    for (int j = 0; j < 2; j++) acc[i][j] = (f32x4){0.f, 0.f, 0.f, 0.f};

  const ushort* Ag = A + (size_t)m0 * K;
  const ushort* Bg = Bw + (size_t)n0 * K;
  const int nt = K >> 6;
  const int s0 = (bid % MTILES) % nt;

  {
    int s1 = s0 + 1; if (s1 >= nt) s1 -= nt;
    stage_sw<MR>(Ag + s0 * 64, K, As, wave, lane, MROWS - 1);
    stage_sw<2>(Bg + s0 * 64, K, Bs, wave, lane, 63);
    stage_sw<MR>(Ag + s1 * 64, K, As + ASZ, wave, lane, MROWS - 1);
    stage_sw<2>(Bg + s1 * 64, K, Bs + BSZ, wave, lane, 63);
  }

  for (int t = 0; t < nt; t++) {
    if (t + 1 < nt) {
      asm volatile("s_waitcnt vmcnt(%0)" :: "i"(MR + 2) : "memory");
    } else {
      asm volatile("s_waitcnt vmcnt(0)" ::: "memory");
    }
    __builtin_amdgcn_s_barrier();
    __builtin_amdgcn_sched_barrier(0);

    const ushort* Ab = As + (t % 3) * ASZ + (wr + la) * 64;
    const ushort* Bb = Bs + (t % 3) * BSZ + (wc + la) * 64;
    __builtin_amdgcn_s_setprio(1);
#pragma unroll
    for (int ks = 0; ks < 2; ks++) {
      const int co = (ks * 32 + hi * 8) ^ swz;
      short8 a[MR], b[2];
#pragma unroll
      for (int mi = 0; mi < MR; mi++)
        a[mi] = *(const short8*)(Ab + mi * 1024 + co);
#pragma unroll
      for (int ni = 0; ni < 2; ni++)
        b[ni] = *(const short8*)(Bb + ni * 1024 + co);
#pragma unroll
      for (int mi = 0; mi < MR; mi++)
#pragma unroll
        for (int ni = 0; ni < 2; ni++)
          acc[mi][ni] = __builtin_amdgcn_mfma_f32_16x16x32_bf16(
              a[mi], b[ni], acc[mi][ni], 0, 0, 0);
    }
    __builtin_amdgcn_s_setprio(0);
    __builtin_amdgcn_sched_barrier(0);
    __builtin_amdgcn_s_barrier();
    __builtin_amdgcn_sched_barrier(0);
    if (t + 2 < nt) {
      int sn = t + 2 + s0; if (sn >= nt) sn -= nt;
      stage_sw<MR>(Ag + sn * 64, K, As + ((t + 2) % 3) * ASZ, wave, lane, MROWS - 1);
      stage_sw<2>(Bg + sn * 64, K, Bs + ((t + 2) % 3) * BSZ, wave, lane, 63);
    }
  }

  if (OUTBF) {
    ushort* L = smem;  // [MROWS][72]
#pragma unroll
    for (int mi = 0; mi < MR; mi++)
#pragma unroll
      for (int ni = 0; ni < 2; ni++)
#pragma unroll
        for (int j = 0; j < 4; j++) {
          const int row = wr + mi * 16 + 4 * hi + j;
          const int col = wc + ni * 16 + la;
          float x = acc[mi][ni][j];
          if (EPI >= 1) x += bias[n0 + col];
          if (EPI == 3) x = 0.5f * x * (1.0f + erff(x * 0.70710678118f));
          L[row * 72 + col] = f2bf(x);
        }
    __syncthreads();
    ushort* Co = (ushort*)Cout;
    constexpr int ITERS = MROWS * 64 / 8 / 256;
#pragma unroll
    for (int it = 0; it < ITERS; it++) {
      const int idx8 = it * 256 + tid;
      const int row = idx8 >> 3, c8 = idx8 & 7;
      short8 v = *(const short8*)&L[row * 72 + c8 * 8];
      *(short8*)&Co[(size_t)(m0 + row) * N + n0 + c8 * 8] = v;
    }
  } else {
    float* L = (float*)smem;  // [MROWS][68]
#pragma unroll
    for (int mi = 0; mi < MR; mi++)
#pragma unroll
      for (int ni = 0; ni < 2; ni++)
#pragma unroll
        for (int j = 0; j < 4; j++) {
          const int row = wr + mi * 16 + 4 * hi + j;
          const int col = wc + ni * 16 + la;
          float x = acc[mi][ni][j];
          if (EPI >= 1) x += bias[n0 + col];
          if (EPI == 3) x = 0.5f * x * (1.0f + erff(x * 0.70710678118f));
          L[row * 68 + col] = x;
        }
    __syncthreads();
    f32x4* Co = (f32x4*)Cout;
    const f32x4* R4 = (const f32x4*)res;
    constexpr int ITERS = MROWS * 64 / 4 / 256;
#pragma unroll
    for (int it = 0; it < ITERS; it++) {
      const int idx4 = it * 256 + tid;
      const int row = idx4 >> 4, c4 = idx4 & 15;
      f32x4 v = *(const f32x4*)&L[row * 68 + c4 * 4];
      const size_t o4 = ((size_t)(m0 + row) * N + n0) / 4 + c4;
      if (EPI == 2) v += R4[o4];
      Co[o4] = v;
    }
  }
}

// ---------------- flash attention, bf16 in/out, async reg staging ----------
__global__ __launch_bounds__(256) void attn_bf(const ushort* __restrict__ qkv,
                                               ushort* __restrict__ o) {
  const int tid = threadIdx.x;
  const int lane = tid & 63;
  const int wave = tid >> 6;
  const int hi = lane >> 4;
  const int la = lane & 15;
  const int q0 = blockIdx.x * 64;
  const int bh = blockIdx.y;
  const int bb = bh / NH;
  const int hh = bh % NH;
  const size_t rstride = 3 * DM;
  const ushort* base = qkv + (size_t)bb * SS * rstride;
  const ushort* kbase = base + DM + hh * HDIM;
  const ushort* vbase = base + 2 * DM + hh * HDIM;

  __shared__ ushort Ks[64][72];
  __shared__ ushort Vt[64][72];
  __shared__ ushort Pb[4][16][72];

  const int kr = tid >> 2;
  const int kc = (tid & 3) * 16;
  const int vp0 = (tid >> 3) * 2;
  const int vc = (tid & 7) * 8;

  short8 qf[2];
  {
    const int qrow = q0 + wave * 16 + la;
    const ushort* qp = base + (size_t)qrow * rstride + hh * HDIM + 8 * hi;
    qf[0] = *(const short8*)qp;
    qf[1] = *(const short8*)(qp + 32);
  }

  short8 kA, kB, vA, vB;
  {
    const ushort* kp = kbase + (size_t)kr * rstride + kc;
    kA = *(const short8*)kp;
    kB = *(const short8*)(kp + 8);
    const ushort* vp = vbase + (size_t)vp0 * rstride + vc;
    vA = *(const short8*)vp;
    vB = *(const short8*)(vp + rstride);
  }

  f32x4 accO[4] = {};
  float m_[4], l_[4];
#pragma unroll
  for (int j = 0; j < 4; j++) { m_[j] = -1e30f; l_[j] = 0.f; }

  const int nt = q0 / 64 + 1;
  for (int kt = 0; kt < nt; kt++) {
    __syncthreads();
    *(short8*)&Ks[kr][kc]     = kA;
    *(short8*)&Ks[kr][kc + 8] = kB;
#pragma unroll
    for (int i = 0; i < 8; i++) {
      unsigned int pk = (unsigned int)(unsigned short)vA[i] |
                        ((unsigned int)(unsigned short)vB[i] << 16);
      *(unsigned int*)&Vt[vc + i][vp0] = pk;
    }
    __syncthreads();
    if (kt + 1 < nt) {
      const ushort* kp = kbase + (size_t)((kt + 1) * 64 + kr) * rstride + kc;
      kA = *(const short8*)kp;
      kB = *(const short8*)(kp + 8);
      const ushort* vp = vbase + (size_t)((kt + 1) * 64 + vp0) * rstride + vc;
      vA = *(const short8*)vp;
      vB = *(const short8*)(vp + rstride);
    }

    f32x4 s[4] = {};
    __builtin_amdgcn_s_setprio(1);
#pragma unroll
    for (int f = 0; f < 4; f++) {
#pragma unroll
      for (int kk = 0; kk < 2; kk++) {
        short8 kf = *(const short8*)&Ks[f * 16 + la][kk * 32 + 8 * hi];
        s[f] = __builtin_amdgcn_mfma_f32_16x16x32_bf16(qf[kk], kf, s[f], 0, 0, 0);
      }
    }
    __builtin_amdgcn_s_setprio(0);
#pragma unroll
    for (int f = 0; f < 4; f++)
#pragma unroll
      for (int j = 0; j < 4; j++) s[f][j] *= 0.125f;

    if (kt == nt - 1) {
      const int qr = wave * 16 + 4 * hi;
#pragma unroll
      for (int f = 0; f < 4; f++) {
        const int kcol = f * 16 + la;
#pragma unroll
        for (int j = 0; j < 4; j++)
          if (kcol > qr + j) s[f][j] = -1e30f;
      }
    }

#pragma unroll
    for (int j = 0; j < 4; j++) {
      float rm = fmaxf(fmaxf(s[0][j], s[1][j]), fmaxf(s[2][j], s[3][j]));
      rm = fmaxf(rm, __shfl_xor(rm, 1));
      rm = fmaxf(rm, __shfl_xor(rm, 2));
      rm = fmaxf(rm, __shfl_xor(rm, 4));
      rm = fmaxf(rm, __shfl_xor(rm, 8));
      const float mnew = fmaxf(m_[j], rm);
      const float alpha = expf(m_[j] - mnew);
      float rs = 0.f;
#pragma unroll
      for (int f = 0; f < 4; f++) {
        const float p = expf(s[f][j] - mnew);
        s[f][j] = p;
        rs += p;
      }
      rs += __shfl_xor(rs, 1);
      rs += __shfl_xor(rs, 2);
      rs += __shfl_xor(rs, 4);
      rs += __shfl_xor(rs, 8);
      l_[j] = l_[j] * alpha + rs;
      m_[j] = mnew;
#pragma unroll
      for (int f = 0; f < 4; f++) accO[f][j] *= alpha;
    }

#pragma unroll
    for (int f = 0; f < 4; f++)
#pragma unroll
      for (int j = 0; j < 4; j++)
        Pb[wave][4 * hi + j][f * 16 + la] = f2bf(s[f][j]);

    short8 pf0 = *(const short8*)&Pb[wave][la][8 * hi];
    short8 pf1 = *(const short8*)&Pb[wave][la][32 + 8 * hi];
    __builtin_amdgcn_s_setprio(1);
#pragma unroll
    for (int f = 0; f < 4; f++) {
      short8 vf0 = *(const short8*)&Vt[f * 16 + la][8 * hi];
      short8 vf1 = *(const short8*)&Vt[f * 16 + la][32 + 8 * hi];
      accO[f] = __builtin_amdgcn_mfma_f32_16x16x32_bf16(pf0, vf0, accO[f], 0, 0, 0);
      accO[f] = __builtin_amdgcn_mfma_f32_16x16x32_bf16(pf1, vf1, accO[f], 0, 0, 0);
    }
    __builtin_amdgcn_s_setprio(0);
  }

  ushort* op = o + (size_t)(bb * SS + q0 + wave * 16) * DM + hh * HDIM;
#pragma unroll
  for (int j = 0; j < 4; j++) {
    const float inv = 1.0f / l_[j];
    const int qr = 4 * hi + j;
#pragma unroll
    for (int f = 0; f < 4; f++)
      op[(size_t)qr * DM + f * 16 + la] = f2bf(accO[f][j] * inv);
  }
}

// ================= legacy fallback (fp32 weights) ============
template <int EPI>
__global__ __launch_bounds__(256) void gemm_nt(const float* __restrict__ A,
    const float* __restrict__ Bw, const float* __restrict__ bias,
    const float* __restrict__ res, float* __restrict__ C, int N, int K) {
  __shared__ ushort As[64][40];
  __shared__ ushort Bs[64][40];
  const int tid = threadIdx.x;
  const int m0 = blockIdx.y * 64;
  const int n0 = blockIdx.x * 64;
  const int lane = tid & 63;
  const int wave = tid >> 6;
  const int wr = (wave >> 1) * 32;
  const int wc = (wave & 1) * 32;
  const int lr = lane & 15;
  const int lk = (lane >> 4) * 8;
  const int sr = tid >> 2;
  const int sc = (tid & 3) * 8;
  f32x4 acc[2][2] = {};
  for (int kk = 0; kk < K; kk += 32) {
    {
      const float* p = A + (size_t)(m0 + sr) * K + kk + sc;
      f32x4 v0 = *(const f32x4*)p;
      f32x4 v1 = *(const f32x4*)(p + 4);
      short8 sv;
      for (int i = 0; i < 4; i++) { sv[i] = f2bf(v0[i]); sv[4 + i] = f2bf(v1[i]); }
      *(short8*)&As[sr][sc] = sv;
    }
    {
      const int gr = n0 + sr;
      short8 sv = {};
      if (gr < N) {
        const float* p = Bw + (size_t)gr * K + kk + sc;
        f32x4 v0 = *(const f32x4*)p;
        f32x4 v1 = *(const f32x4*)(p + 4);
        for (int i = 0; i < 4; i++) { sv[i] = f2bf(v0[i]); sv[4 + i] = f2bf(v1[i]); }
      }
      *(short8*)&Bs[sr][sc] = sv;
    }
    __syncthreads();
    short8 a0 = *(const short8*)&As[wr + lr][lk];
    short8 a1 = *(const short8*)&As[wr + 16 + lr][lk];
    short8 b0 = *(const short8*)&Bs[wc + lr][lk];
    short8 b1 = *(const short8*)&Bs[wc + 16 + lr][lk];
    acc[0][0] = __builtin_amdgcn_mfma_f32_16x16x32_bf16(a0, b0, acc[0][0], 0, 0, 0);
    acc[0][1] = __builtin_amdgcn_mfma_f32_16x16x32_bf16(a0, b1, acc[0][1], 0, 0, 0);
    acc[1][0] = __builtin_amdgcn_mfma_f32_16x16x32_bf16(a1, b0, acc[1][0], 0, 0, 0);
    acc[1][1] = __builtin_amdgcn_mfma_f32_16x16x32_bf16(a1, b1, acc[1][1], 0, 0, 0);
    __syncthreads();
  }
  const int orow = (lane >> 4) * 4;
  for (int mi = 0; mi < 2; mi++)
    for (int ni = 0; ni < 2; ni++) {
      const int col = n0 + wc + ni * 16 + lr;
      if (col >= N) continue;
      for (int j = 0; j < 4; j++) {
        const int row = m0 + wr + mi * 16 + orow + j;
        float x = acc[mi][ni][j];
        if (EPI >= 1) x += bias[col];
        const size_t idx = (size_t)row * N + col;
        if (EPI == 2) x += res[idx];
        if (EPI == 3) x = 0.5f * x * (1.0f + erff(x * 0.70710678118f));
        C[idx] = x;
      }
    }
}

__global__ __launch_bounds__(256) void attn_f32(const float* __restrict__ qkv,
                                                float* __restrict__ o) {
  const int tid = threadIdx.x;
  const int lane = tid & 63;
  const int wave = tid >> 6;
  const int hi = lane >> 4;
  const int la = lane & 15;
  const int q0 = blockIdx.x * 64;
  const int bh = blockIdx.y;
  const int bb = bh / NH;
  const int hh = bh % NH;
  const size_t rstride = 3 * DM;
  const float* base = qkv + (size_t)bb * SS * rstride;
  __shared__ ushort Ks[64][72];
  __shared__ ushort Vt[64][72];
  __shared__ ushort Pb[4][16][72];
  short8 qf[2];
  {
    const int qrow = q0 + wave * 16 + la;
    const float* qp = base + (size_t)qrow * rstride + hh * HDIM + 8 * hi;
    for (int kk = 0; kk < 2; kk++) {
      f32x4 v0 = *(const f32x4*)(qp + 32 * kk);
      f32x4 v1 = *(const f32x4*)(qp + 32 * kk + 4);
      short8 sv;
      for (int i = 0; i < 4; i++) {
        sv[i] = f2bf(v0[i] * 0.125f); sv[4 + i] = f2bf(v1[i] * 0.125f);
      }
      qf[kk] = sv;
    }
  }
  f32x4 accO[4] = {};
  float m_[4], l_[4];
  for (int j = 0; j < 4; j++) { m_[j] = -1e30f; l_[j] = 0.f; }
  const int nt = q0 / 64 + 1;
  for (int kt = 0; kt < nt; kt++) {
    __syncthreads();
    {
      const int r = tid >> 2;
      const int c = (tid & 3) * 16;
      const float* kp = base + (size_t)(kt * 64 + r) * rstride + DM + hh * HDIM + c;
      const float* vp = kp + DM;
      f32x4 k0 = *(const f32x4*)kp, k1 = *(const f32x4*)(kp + 4);
      f32x4 k2 = *(const f32x4*)(kp + 8), k3 = *(const f32x4*)(kp + 12);
      short8 s0, s1;
      for (int i = 0; i < 4; i++) {
        s0[i] = f2bf(k0[i]); s0[4 + i] = f2bf(k1[i]);
        s1[i] = f2bf(k2[i]); s1[4 + i] = f2bf(k3[i]);
      }
      *(short8*)&Ks[r][c] = s0;
      *(short8*)&Ks[r][c + 8] = s1;
      f32x4 v0 = *(const f32x4*)vp, v1 = *(const f32x4*)(vp + 4);
      f32x4 v2 = *(const f32x4*)(vp + 8), v3 = *(const f32x4*)(vp + 12);
      for (int i = 0; i < 4; i++) {
        Vt[c + i][r] = f2bf(v0[i]); Vt[c + 4 + i][r] = f2bf(v1[i]);
        Vt[c + 8 + i][r] = f2bf(v2[i]); Vt[c + 12 + i][r] = f2bf(v3[i]);
      }
    }
    __syncthreads();
    f32x4 s[4] = {};
    for (int f = 0; f < 4; f++)
      for (int kk = 0; kk < 2; kk++) {
        short8 kf = *(const short8*)&Ks[f * 16 + la][kk * 32 + 8 * hi];
        s[f] = __builtin_amdgcn_mfma_f32_16x16x32_bf16(qf[kk], kf, s[f], 0, 0, 0);
      }
    if (kt == nt - 1) {
      const int qr = wave * 16 + 4 * hi;
      for (int f = 0; f < 4; f++) {
        const int kcol = f * 16 + la;
        for (int j = 0; j < 4; j++)
          if (kcol > qr + j) s[f][j] = -1e30f;
      }
    }
    for (int j = 0; j < 4; j++) {
      float rm = fmaxf(fmaxf(s[0][j], s[1][j]), fmaxf(s[2][j], s[3][j]));
      rm = fmaxf(rm, __shfl_xor(rm, 1));
      rm = fmaxf(rm, __shfl_xor(rm, 2));
      rm = fmaxf(rm, __shfl_xor(rm, 4));
      rm = fmaxf(rm, __shfl_xor(rm, 8));
      const float mnew = fmaxf(m_[j], rm);
      const float alpha = expf(m_[j] - mnew);
      float rs = 0.f;
      for (int f = 0; f < 4; f++) {
        const float p = expf(s[f][j] - mnew);
        s[f][j] = p; rs += p;
      }
      rs += __shfl_xor(rs, 1);
      rs += __shfl_xor(rs, 2);
      rs += __shfl_xor(rs, 4);
      rs += __shfl_xor(rs, 8);
      l_[j] = l_[j] * alpha + rs;
      m_[j] = mnew;
      for (int f = 0; f < 4; f++) accO[f][j] *= alpha;
    }
    for (int f = 0; f < 4; f++)
      for (int j = 0; j < 4; j++)
        Pb[wave][4 * hi + j][f * 16 + la] = f2bf(s[f][j]);
    short8 pf0 = *(const short8*)&Pb[wave][la][8 * hi];
    short8 pf1 = *(const short8*)&Pb[wave][la][32 + 8 * hi];
    for (int f = 0; f < 4; f++) {
      short8 vf0 = *(const short8*)&Vt[f * 16 + la][8 * hi];
      short8 vf1 = *(const short8*)&Vt[f * 16 + la][32 + 8 * hi];
      accO[f] = __builtin_amdgcn_mfma_f32_16x16x32_bf16(pf0, vf0, accO[f], 0, 0, 0);
      accO[f] = __builtin_amdgcn_mfma_f32_16x16x32_bf16(pf1, vf1, accO[f], 0, 0, 0);
    }
  }
  float* op = o + (size_t)(bb * SS + q0 + wave * 16) * DM + hh * HDIM;
  for (int j = 0; j < 4; j++) {
    const float inv = 1.0f / l_[j];
    const int qr = 4 * hi + j;
    for (int f = 0; f < 4; f++)
      op[(size_t)qr * DM + f * 16 + la] = accO[f][j] * inv;
  }
}

// ---------------- host launcher ----------------
extern "C" void kernel_launch(void* const* d_in, const int* in_sizes, int n_in,
                              void* d_out, int out_size, void* d_ws,
                              size_t ws_size, hipStream_t stream) {
  const int*   ids     = (const int*)d_in[0];
  const float* wte     = (const float*)d_in[1];
  const float* wpe     = (const float*)d_in[2];
  const float* ln1_g   = (const float*)d_in[3];
  const float* ln1_b   = (const float*)d_in[4];
  const float* qkv_w   = (const float*)d_in[5];
  const float* qkv_b   = (const float*)d_in[6];
  const float* proj_w  = (const float*)d_in[7];
  const float* proj_b  = (const float*)d_in[8];
  const float* ln2_g   = (const float*)d_in[9];
  const float* ln2_b   = (const float*)d_in[10];
  const float* fc_w    = (const float*)d_in[11];
  const float* fc_b    = (const float*)d_in[12];
  const float* cproj_w = (const float*)d_in[13];
  const float* cproj_b = (const float*)d_in[14];
  const float* lnf_g   = (const float*)d_in[15];
  const float* lnf_b   = (const float*)d_in[16];
  float* out = (float*)d_out;

  const size_t sz_h    = (size_t)ROWS * DM * 4;
  const size_t sz_hn   = (size_t)ROWS * DM * 2;
  const size_t sz_qkv  = (size_t)ROWS * 3 * DM * 2;
  const size_t sz_ob   = (size_t)ROWS * DM * 2;
  const size_t sz_mb   = (size_t)ROWS * DFFN * 2;
  const size_t sz_wq   = (size_t)NL * 3 * DM * DM * 2;
  const size_t sz_wp   = (size_t)NL * DM * DM * 2;
  const size_t sz_wf   = (size_t)NL * DFFN * DM * 2;
  const size_t sz_wc   = (size_t)NL * DM * DFFN * 2;
  const size_t sz_wt   = (size_t)VOC * DM * 2;
  const size_t NEED = sz_h + sz_hn + sz_qkv + sz_ob + sz_mb +
                      sz_wq + sz_wp + sz_wf + sz_wc + sz_wt;

  if (ws_size >= NEED) {
    char* p = (char*)d_ws;
    float*  h    = (float*)p;  p += sz_h;
    ushort* hn   = (ushort*)p; p += sz_hn;
    ushort* qkvb = (ushort*)p; p += sz_qkv;
    ushort* ob   = (ushort*)p; p += sz_ob;
    ushort* mb   = (ushort*)p; p += sz_mb;
    ushort* wq   = (ushort*)p; p += sz_wq;
    ushort* wp   = (ushort*)p; p += sz_wp;
    ushort* wf   = (ushort*)p; p += sz_wf;
    ushort* wc   = (ushort*)p; p += sz_wc;
    ushort* wt   = (ushort*)p; p += sz_wt;

    f2b_k<<<2048, 256, 0, stream>>>(qkv_w,   wq, NL * 3 * DM * DM / 4);
    f2b_k<<<1024, 256, 0, stream>>>(proj_w,  wp, NL * DM * DM / 4);
    f2b_k<<<2048, 256, 0, stream>>>(fc_w,    wf, NL * DFFN * DM / 4);
    f2b_k<<<2048, 256, 0, stream>>>(cproj_w, wc, NL * DM * DFFN / 4);
    f2b_k<<<2048, 256, 0, stream>>>(wte,     wt, VOC * DM / 4);

    embed_k<<<ROWS, 256, 0, stream>>>(ids, wte, wpe, h);

    for (int l = 0; l < NL; l++) {
      layernorm_t<1><<<ROWS / 4, 256, 0, stream>>>(h, ln1_g + l * DM, ln1_b + l * DM, hn);
      gemm_p3<1, 1, 4><<<MT * (3 * DM / 64), 256, 0, stream>>>(
          hn, wq + (size_t)l * 3 * DM * DM, qkv_b + (size_t)l * 3 * DM,
          nullptr, qkvb, 3 * DM, DM);
      attn_bf<<<dim3(SS / 64, BB * NH), 256, 0, stream>>>(qkvb, ob);
      gemm_p3<2, 0, 2><<<(ROWS / 64) * (DM / 64), 256, 0, stream>>>(
          ob, wp + (size_t)l * DM * DM, proj_b + (size_t)l * DM, h, h, DM, DM);
      layernorm_t<1><<<ROWS / 4, 256, 0, stream>>>(h, ln2_g + l * DM, ln2_b + l * DM, hn);
      gemm_p3<3, 1, 4><<<MT * (DFFN / 64), 256, 0, stream>>>(
          hn, wf + (size_t)l * DFFN * DM, fc_b + (size_t)l * DFFN,
          nullptr, mb, DFFN, DM);
      gemm_p3<2, 0, 2><<<(ROWS / 64) * (DM / 64), 256, 0, stream>>>(
          mb, wc + (size_t)l * DM * DFFN, cproj_b + (size_t)l * DM, h, h,
          DM, DFFN);
    }

    layernorm_t<1><<<ROWS / 4, 256, 0, stream>>>(h, lnf_g, lnf_b, hn);
    gemm_256<<<8 * ((VOC + 255) / 256), 512, 0, stream>>>(
        hn, wt, out, VOC, DM);
  } else {
    float* ws = (float*)d_ws;
    float* h   = ws;
    float* hn  = h + (size_t)ROWS * DM;
    float* qkv = hn + (size_t)ROWS * DM;
    float* ob  = qkv + (size_t)ROWS * 3 * DM;
    float* mb  = ob + (size_t)ROWS * DM;

    embed_k<<<ROWS, 256, 0, stream>>>(ids, wte, wpe, h);
    for (int l = 0; l < NL; l++) {
      layernorm_t<0><<<ROWS / 4, 256, 0, stream>>>(h, ln1_g + l * DM, ln1_b + l * DM, hn);
      gemm_nt<1><<<dim3(3 * DM / 64, ROWS / 64), 256, 0, stream>>>(
          hn, qkv_w + (size_t)l * 3 * DM * DM, qkv_b + (size_t)l * 3 * DM,
          nullptr, qkv, 3 * DM, DM);
      attn_f32<<<dim3(SS / 64, BB * NH), 256, 0, stream>>>(qkv, ob);
      gemm_nt<2><<<dim3(DM / 64, ROWS / 64), 256, 0, stream>>>(
          ob, proj_w + (size_t)l * DM * DM, proj_b + (size_t)l * DM, h, h, DM, DM);
      layernorm_t<0><<<ROWS / 4, 256, 0, stream>>>(h, ln2_g + l * DM, ln2_b + l * DM, hn);
      gemm_nt<3><<<dim3(DFFN / 64, ROWS / 64), 256, 0, stream>>>(
          hn, fc_w + (size_t)l * DFFN * DM, fc_b + (size_t)l * DFFN,
          nullptr, mb, DFFN, DM);
      gemm_nt<2><<<dim3(DM / 64, ROWS / 64), 256, 0, stream>>>(
          mb, cproj_w + (size_t)l * DM * DFFN, cproj_b + (size_t)l * DM, h, h,
          DM, DFFN);
    }
    layernorm_t<0><<<ROWS / 4, 256, 0, stream>>>(h, lnf_g, lnf_b, hn);
    gemm_nt<0><<<dim3((VOC + 63) / 64, ROWS / 64), 256, 0, stream>>>(
        hn, wte, nullptr, nullptr, out, VOC, DM);
  }
}

// Round 13
// 2013.032 us; speedup vs baseline: 1.0294x; 1.0294x over previous
//
#include <hip/hip_runtime.h>

// GPT-2 small forward: B=2, S=1024, D=768, H=12, HD=64, L=12, DFF=3072, V=50257
#define BB 2
#define SS 1024
#define DM 768
#define NH 12
#define HDIM 64
#define NL 12
#define DFFN 3072
#define VOC 50257
#define ROWS (BB * SS)   // 2048
#define MT (ROWS / 128)  // 16 M-tiles for 128-row GEMMs

typedef __attribute__((ext_vector_type(4))) float f32x4;
typedef __attribute__((ext_vector_type(8))) short short8;
typedef __attribute__((ext_vector_type(4))) short short4v;
typedef unsigned short ushort;

__device__ __forceinline__ ushort f2bf(float f) {
  union { float f; unsigned int u; } x; x.f = f;
  unsigned int u = x.u;
  unsigned int r = (u + 0x7FFFu + ((u >> 16) & 1u)) >> 16;
  return (ushort)r;
}

// ---------------- embedding (vectorized f32x4 grid-stride) ----------------
__global__ __launch_bounds__(256) void embed_k(const int* __restrict__ ids,
    const float* __restrict__ wte, const float* __restrict__ wpe,
    float* __restrict__ h) {
  const int total = ROWS * (DM / 4);   // 393216 vec4
  for (int i = blockIdx.x * 256 + threadIdx.x; i < total; i += gridDim.x * 256) {
    const int row = i / (DM / 4);
    const int col = i - row * (DM / 4);
    const int s = row & (SS - 1);
    const int id = ids[row];
    f32x4 w = ((const f32x4*)(wte + (size_t)id * DM))[col];
    f32x4 p = ((const f32x4*)(wpe + (size_t)s * DM))[col];
    ((f32x4*)(h + (size_t)row * DM))[col] = w + p;
  }
}

// ---------------- merged fp32 -> bf16 weight conversion ----------------
__global__ __launch_bounds__(256) void f2b_all(
    const float* __restrict__ s0, const float* __restrict__ s1,
    const float* __restrict__ s2, const float* __restrict__ s3,
    const float* __restrict__ s4, ushort* __restrict__ d0,
    ushort* __restrict__ d1, ushort* __restrict__ d2,
    ushort* __restrict__ d3, ushort* __restrict__ d4) {
  const int n0 = NL * 3 * DM * DM / 4;   // qkv_w
  const int n1 = NL * DM * DM / 4;       // proj_w
  const int n2 = NL * DFFN * DM / 4;     // fc_w
  const int n3 = NL * DM * DFFN / 4;     // cproj_w
  const int n4 = VOC * DM / 4;           // wte
  const int total = n0 + n1 + n2 + n3 + n4;
  for (int i = blockIdx.x * 256 + threadIdx.x; i < total; i += gridDim.x * 256) {
    const float* s; ushort* d; int j = i;
    if (j < n0) { s = s0; d = d0; }
    else { j -= n0;
      if (j < n1) { s = s1; d = d1; }
      else { j -= n1;
        if (j < n2) { s = s2; d = d2; }
        else { j -= n2;
          if (j < n3) { s = s3; d = d3; }
          else { j -= n3; s = s4; d = d4; }
        }
      }
    }
    f32x4 v = ((const f32x4*)s)[j];
    short4v o;
    o[0] = f2bf(v[0]); o[1] = f2bf(v[1]); o[2] = f2bf(v[2]); o[3] = f2bf(v[3]);
    ((short4v*)d)[j] = o;
  }
}

// legacy single-tensor convert (fallback path)
__global__ __launch_bounds__(256) void f2b_k(const float* __restrict__ in,
                                             ushort* __restrict__ out, int n4) {
  for (int i = blockIdx.x * 256 + threadIdx.x; i < n4; i += gridDim.x * 256) {
    f32x4 v = ((const f32x4*)in)[i];
    short4v s;
    s[0] = f2bf(v[0]); s[1] = f2bf(v[1]); s[2] = f2bf(v[2]); s[3] = f2bf(v[3]);
    ((short4v*)out)[i] = s;
  }
}

// ---------------- layernorm: one WAVE per row, shuffle-only ----------------
template <int OB>
__global__ __launch_bounds__(256) void layernorm_t(const float* __restrict__ x,
    const float* __restrict__ g, const float* __restrict__ b, void* __restrict__ y) {
  const int tid = threadIdx.x;
  const int lane = tid & 63;
  const int wave = tid >> 6;
  const int row = blockIdx.x * 4 + wave;
  const size_t base = (size_t)row * DM;

  f32x4 v[3];
  float sum = 0.f;
#pragma unroll
  for (int k = 0; k < 3; k++) {
    v[k] = *(const f32x4*)&x[base + k * 256 + lane * 4];
    sum += v[k][0] + v[k][1] + v[k][2] + v[k][3];
  }
#pragma unroll
  for (int off = 32; off >= 1; off >>= 1) sum += __shfl_xor(sum, off);
  const float mu = sum * (1.0f / DM);

  float var = 0.f;
#pragma unroll
  for (int k = 0; k < 3; k++)
#pragma unroll
    for (int i = 0; i < 4; i++) {
      const float d = v[k][i] - mu;
      var += d * d;
    }
#pragma unroll
  for (int off = 32; off >= 1; off >>= 1) var += __shfl_xor(var, off);
  const float rstd = rsqrtf(var * (1.0f / DM) + 1e-5f);

#pragma unroll
  for (int k = 0; k < 3; k++) {
    const int col = k * 256 + lane * 4;
    f32x4 gv = *(const f32x4*)&g[col];
    f32x4 bv = *(const f32x4*)&b[col];
    if (OB) {
      short4v o;
#pragma unroll
      for (int i = 0; i < 4; i++)
        o[i] = f2bf((v[k][i] - mu) * rstd * gv[i] + bv[i]);
      *(short4v*)&((ushort*)y)[base + col] = o;
    } else {
      f32x4 o;
#pragma unroll
      for (int i = 0; i < 4; i++)
        o[i] = (v[k][i] - mu) * rstd * gv[i] + bv[i];
      *(f32x4*)&((float*)y)[base + col] = o;
    }
  }
}

// -------- async stage (4 waves), T2 pre-swizzled source, linear LDS dest ---
template <int ROUNDS>
__device__ __forceinline__ void stage_sw(const ushort* __restrict__ g, int ldg,
                                         ushort* lds, int wave, int lane,
                                         int rowmax) {
#pragma unroll
  for (int r = 0; r < ROUNDS; r++) {
    const int chunk = (r * 4 + wave) * 64 + lane;
    const int nrow = chunk >> 3;
    const int cs = (chunk & 7) ^ (nrow & 7);
    const int row = nrow > rowmax ? rowmax : nrow;
    const ushort* ga = g + (size_t)row * ldg + cs * 8;
    ushort* la = lds + (r * 4 + wave) * 512;
    __builtin_amdgcn_global_load_lds(
        (const __attribute__((address_space(1))) unsigned int*)ga,
        (__attribute__((address_space(3))) unsigned int*)la, 16, 0, 0);
  }
}

// ---------------- logits GEMM: 128x128 tile, depth-1 counted vmcnt ---------
__global__ __launch_bounds__(256) void gemm_lg(const ushort* __restrict__ A,
    const ushort* __restrict__ Bw, float* __restrict__ Cout, int N, int K) {
  __shared__ __align__(16) ushort smem[4 * 8192];   // 64 KB
  ushort* AsL0 = smem;
  ushort* AsL1 = smem + 8192;
  ushort* BsL0 = smem + 16384;
  ushort* BsL1 = smem + 24576;

  const int tid = threadIdx.x;
  const int lane = tid & 63;
  const int wave = tid >> 6;
  const int la = lane & 15;
  const int hi = lane >> 4;
  const int swz = (la & 7) << 3;

  const int nwg = gridDim.x;
  int bid = blockIdx.x;
  {
    const int q = nwg >> 3, r = nwg & 7;
    const int xcd = bid & 7, idx = bid >> 3;
    bid = (xcd < r ? xcd * (q + 1) : r * (q + 1) + (xcd - r) * q) + idx;
  }
  const int m0 = (bid % MT) * 128;
  const int n0 = (bid / MT) * 128;

  const int wr = (wave >> 1) * 64;
  const int wc = (wave & 1) * 64;
  const int brmax = min(N - n0 - 1, 127);

  f32x4 acc[4][4];
#pragma unroll
  for (int i = 0; i < 4; i++)
#pragma unroll
    for (int j = 0; j < 4; j++) acc[i][j] = (f32x4){0.f, 0.f, 0.f, 0.f};

  const ushort* Ag = A + (size_t)m0 * K;
  const ushort* Bg = Bw + (size_t)n0 * K;

  const int nt = K >> 6;
  const int s0 = (bid % MT) % nt;

  stage_sw<4>(Ag + s0 * 64, K, AsL0, wave, lane, 127);
  stage_sw<4>(Bg + s0 * 64, K, BsL0, wave, lane, brmax);

  int cur = 0;
  for (int t = 0; t < nt; t++) {
    if (t + 1 < nt) {
      int sn = t + 1 + s0; if (sn >= nt) sn -= nt;
      stage_sw<4>(Ag + sn * 64, K, cur ? AsL0 : AsL1, wave, lane, 127);
      stage_sw<4>(Bg + sn * 64, K, cur ? BsL0 : BsL1, wave, lane, brmax);
      asm volatile("s_waitcnt vmcnt(8)" ::: "memory");
    } else {
      asm volatile("s_waitcnt vmcnt(0)" ::: "memory");
    }
    __builtin_amdgcn_s_barrier();
    __builtin_amdgcn_sched_barrier(0);

    const ushort* Ab = (cur ? AsL1 : AsL0) + (wr + la) * 64;
    const ushort* Bb = (cur ? BsL1 : BsL0) + (wc + la) * 64;
    __builtin_amdgcn_s_setprio(1);
#pragma unroll
    for (int ks = 0; ks < 2; ks++) {
      const int co = (ks * 32 + hi * 8) ^ swz;
      short8 a[4], b[4];
#pragma unroll
      for (int mi = 0; mi < 4; mi++)
        a[mi] = *(const short8*)(Ab + mi * 1024 + co);
#pragma unroll
      for (int ni = 0; ni < 4; ni++)
        b[ni] = *(const short8*)(Bb + ni * 1024 + co);
#pragma unroll
      for (int mi = 0; mi < 4; mi++)
#pragma unroll
        for (int ni = 0; ni < 4; ni++)
          acc[mi][ni] = __builtin_amdgcn_mfma_f32_16x16x32_bf16(
              a[mi], b[ni], acc[mi][ni], 0, 0, 0);
    }
    __builtin_amdgcn_s_setprio(0);
    __builtin_amdgcn_sched_barrier(0);
    __builtin_amdgcn_s_barrier();
    __builtin_amdgcn_sched_barrier(0);
    cur ^= 1;
  }

  // ---- two-half f32 LDS-transpose epilogue ----
  float* L = (float*)smem;   // [128][68]
  const int myhalf = wave & 1;
#pragma unroll
  for (int h = 0; h < 2; h++) {
    if (myhalf == h) {
#pragma unroll
      for (int mi = 0; mi < 4; mi++)
#pragma unroll
        for (int ni = 0; ni < 4; ni++)
#pragma unroll
          for (int j = 0; j < 4; j++) {
            const int row = wr + mi * 16 + 4 * hi + j;
            const int col = ni * 16 + la;
            L[row * 68 + col] = acc[mi][ni][j];
          }
    }
    __syncthreads();
#pragma unroll
    for (int it = 0; it < 32; it++) {
      const int flat = it * 256 + tid;       // 0..8191
      const int row = flat >> 6, col = flat & 63;
      const int gc = n0 + h * 64 + col;
      if (gc < N)
        Cout[(size_t)(m0 + row) * N + gc] = L[row * 68 + col];
    }
    __syncthreads();
  }
}

// -------- layer GEMM: MROWS x 64 tile, 3-buffer depth-2, K-stagger ---------
template <int EPI, int OUTBF, int MR>
__global__ __launch_bounds__(256) void gemm_p3(const ushort* __restrict__ A,
    const ushort* __restrict__ Bw, const float* __restrict__ bias,
    const float* __restrict__ res, void* __restrict__ Cout, int N, int K) {
  constexpr int MROWS = MR * 32;
  constexpr int MTILES = ROWS / MROWS;
  constexpr int ASZ = MROWS * 64;
  constexpr int BSZ = 64 * 64;
  __shared__ __align__(16) ushort smem[3 * ASZ + 3 * BSZ];
  ushort* As = smem;
  ushort* Bs = smem + 3 * ASZ;

  const int tid = threadIdx.x;
  const int lane = tid & 63;
  const int wave = tid >> 6;
  const int la = lane & 15;
  const int hi = lane >> 4;
  const int swz = (la & 7) << 3;

  const int nwg = gridDim.x;
  int bid = blockIdx.x;
  {
    const int q = nwg >> 3, r = nwg & 7;
    const int xcd = bid & 7, idx = bid >> 3;
    bid = (xcd < r ? xcd * (q + 1) : r * (q + 1) + (xcd - r) * q) + idx;
  }
  const int m0 = (bid % MTILES) * MROWS;
  const int n0 = (bid / MTILES) * 64;

  const int wr = (wave >> 1) * (MROWS / 2);
  const int wc = (wave & 1) * 32;

  f32x4 acc[MR][2];
#pragma unroll
  for (int i = 0; i < MR; i++)
#pragma unroll
    for (int j = 0; j < 2; j++) acc[i][j] = (f32x4){0.f, 0.f, 0.f, 0.f};

  const ushort* Ag = A + (size_t)m0 * K;
  const ushort* Bg = Bw + (size_t)n0 * K;
  const int nt = K >> 6;
  const int s0 = (bid % MTILES) % nt;

  {
    int s1 = s0 + 1; if (s1 >= nt) s1 -= nt;
    stage_sw<MR>(Ag + s0 * 64, K, As, wave, lane, MROWS - 1);
    stage_sw<2>(Bg + s0 * 64, K, Bs, wave, lane, 63);
    stage_sw<MR>(Ag + s1 * 64, K, As + ASZ, wave, lane, MROWS - 1);
    stage_sw<2>(Bg + s1 * 64, K, Bs + BSZ, wave, lane, 63);
  }

  for (int t = 0; t < nt; t++) {
    if (t + 1 < nt) {
      asm volatile("s_waitcnt vmcnt(%0)" :: "i"(MR + 2) : "memory");
    } else {
      asm volatile("s_waitcnt vmcnt(0)" ::: "memory");
    }
    __builtin_amdgcn_s_barrier();
    __builtin_amdgcn_sched_barrier(0);

    const ushort* Ab = As + (t % 3) * ASZ + (wr + la) * 64;
    const ushort* Bb = Bs + (t % 3) * BSZ + (wc + la) * 64;
    __builtin_amdgcn_s_setprio(1);
#pragma unroll
    for (int ks = 0; ks < 2; ks++) {
      const int co = (ks * 32 + hi * 8) ^ swz;
      short8 a[MR], b[2];
#pragma unroll
      for (int mi = 0; mi < MR; mi++)
        a[mi] = *(const short8*)(Ab + mi * 1024 + co);
#pragma unroll
      for (int ni = 0; ni < 2; ni++)
        b[ni] = *(const short8*)(Bb + ni * 1024 + co);
#pragma unroll
      for (int mi = 0; mi < MR; mi++)
#pragma unroll
        for (int ni = 0; ni < 2; ni++)
          acc[mi][ni] = __builtin_amdgcn_mfma_f32_16x16x32_bf16(
              a[mi], b[ni], acc[mi][ni], 0, 0, 0);
    }
    __builtin_amdgcn_s_setprio(0);
    __builtin_amdgcn_sched_barrier(0);
    __builtin_amdgcn_s_barrier();
    __builtin_amdgcn_sched_barrier(0);
    if (t + 2 < nt) {
      int sn = t + 2 + s0; if (sn >= nt) sn -= nt;
      stage_sw<MR>(Ag + sn * 64, K, As + ((t + 2) % 3) * ASZ, wave, lane, MROWS - 1);
      stage_sw<2>(Bg + sn * 64, K, Bs + ((t + 2) % 3) * BSZ, wave, lane, 63);
    }
  }

  if (OUTBF) {
    ushort* L = smem;  // [MROWS][72]
#pragma unroll
    for (int mi = 0; mi < MR; mi++)
#pragma unroll
      for (int ni = 0; ni < 2; ni++)
#pragma unroll
        for (int j = 0; j < 4; j++) {
          const int row = wr + mi * 16 + 4 * hi + j;
          const int col = wc + ni * 16 + la;
          float x = acc[mi][ni][j];
          if (EPI >= 1) x += bias[n0 + col];
          if (EPI == 3) x = 0.5f * x * (1.0f + erff(x * 0.70710678118f));
          L[row * 72 + col] = f2bf(x);
        }
    __syncthreads();
    ushort* Co = (ushort*)Cout;
    constexpr int ITERS = MROWS * 64 / 8 / 256;
#pragma unroll
    for (int it = 0; it < ITERS; it++) {
      const int idx8 = it * 256 + tid;
      const int row = idx8 >> 3, c8 = idx8 & 7;
      short8 v = *(const short8*)&L[row * 72 + c8 * 8];
      *(short8*)&Co[(size_t)(m0 + row) * N + n0 + c8 * 8] = v;
    }
  } else {
    float* L = (float*)smem;  // [MROWS][68]
#pragma unroll
    for (int mi = 0; mi < MR; mi++)
#pragma unroll
      for (int ni = 0; ni < 2; ni++)
#pragma unroll
        for (int j = 0; j < 4; j++) {
          const int row = wr + mi * 16 + 4 * hi + j;
          const int col = wc + ni * 16 + la;
          float x = acc[mi][ni][j];
          if (EPI >= 1) x += bias[n0 + col];
          if (EPI == 3) x = 0.5f * x * (1.0f + erff(x * 0.70710678118f));
          L[row * 68 + col] = x;
        }
    __syncthreads();
    f32x4* Co = (f32x4*)Cout;
    const f32x4* R4 = (const f32x4*)res;
    constexpr int ITERS = MROWS * 64 / 4 / 256;
#pragma unroll
    for (int it = 0; it < ITERS; it++) {
      const int idx4 = it * 256 + tid;
      const int row = idx4 >> 4, c4 = idx4 & 15;
      f32x4 v = *(const f32x4*)&L[row * 68 + c4 * 4];
      const size_t o4 = ((size_t)(m0 + row) * N + n0) / 4 + c4;
      if (EPI == 2) v += R4[o4];
      Co[o4] = v;
    }
  }
}

// ---------------- flash attention, bf16 in/out, async reg staging ----------
__global__ __launch_bounds__(256) void attn_bf(const ushort* __restrict__ qkv,
                                               ushort* __restrict__ o) {
  const int tid = threadIdx.x;
  const int lane = tid & 63;
  const int wave = tid >> 6;
  const int hi = lane >> 4;
  const int la = lane & 15;
  const int q0 = blockIdx.x * 64;
  const int bh = blockIdx.y;
  const int bb = bh / NH;
  const int hh = bh % NH;
  const size_t rstride = 3 * DM;
  const ushort* base = qkv + (size_t)bb * SS * rstride;
  const ushort* kbase = base + DM + hh * HDIM;
  const ushort* vbase = base + 2 * DM + hh * HDIM;

  __shared__ ushort Ks[64][72];
  __shared__ ushort Vt[64][72];
  __shared__ ushort Pb[4][16][72];

  const int kr = tid >> 2;
  const int kc = (tid & 3) * 16;
  const int vp0 = (tid >> 3) * 2;
  const int vc = (tid & 7) * 8;

  short8 qf[2];
  {
    const int qrow = q0 + wave * 16 + la;
    const ushort* qp = base + (size_t)qrow * rstride + hh * HDIM + 8 * hi;
    qf[0] = *(const short8*)qp;
    qf[1] = *(const short8*)(qp + 32);
  }

  short8 kA, kB, vA, vB;
  {
    const ushort* kp = kbase + (size_t)kr * rstride + kc;
    kA = *(const short8*)kp;
    kB = *(const short8*)(kp + 8);
    const ushort* vp = vbase + (size_t)vp0 * rstride + vc;
    vA = *(const short8*)vp;
    vB = *(const short8*)(vp + rstride);
  }

  f32x4 accO[4] = {};
  float m_[4], l_[4];
#pragma unroll
  for (int j = 0; j < 4; j++) { m_[j] = -1e30f; l_[j] = 0.f; }

  const int nt = q0 / 64 + 1;
  for (int kt = 0; kt < nt; kt++) {
    __syncthreads();
    *(short8*)&Ks[kr][kc]     = kA;
    *(short8*)&Ks[kr][kc + 8] = kB;
#pragma unroll
    for (int i = 0; i < 8; i++) {
      unsigned int pk = (unsigned int)(unsigned short)vA[i] |
                        ((unsigned int)(unsigned short)vB[i] << 16);
      *(unsigned int*)&Vt[vc + i][vp0] = pk;
    }
    __syncthreads();
    if (kt + 1 < nt) {
      const ushort* kp = kbase + (size_t)((kt + 1) * 64 + kr) * rstride + kc;
      kA = *(const short8*)kp;
      kB = *(const short8*)(kp + 8);
      const ushort* vp = vbase + (size_t)((kt + 1) * 64 + vp0) * rstride + vc;
      vA = *(const short8*)vp;
      vB = *(const short8*)(vp + rstride);
    }

    f32x4 s[4] = {};
#pragma unroll
    for (int f = 0; f < 4; f++) {
#pragma unroll
      for (int kk = 0; kk < 2; kk++) {
        short8 kf = *(const short8*)&Ks[f * 16 + la][kk * 32 + 8 * hi];
        s[f] = __builtin_amdgcn_mfma_f32_16x16x32_bf16(qf[kk], kf, s[f], 0, 0, 0);
      }
#pragma unroll
      for (int j = 0; j < 4; j++) s[f][j] *= 0.125f;
    }

    if (kt == nt - 1) {
      const int qr = wave * 16 + 4 * hi;
#pragma unroll
      for (int f = 0; f < 4; f++) {
        const int kcol = f * 16 + la;
#pragma unroll
        for (int j = 0; j < 4; j++)
          if (kcol > qr + j) s[f][j] = -1e30f;
      }
    }

#pragma unroll
    for (int j = 0; j < 4; j++) {
      float rm = fmaxf(fmaxf(s[0][j], s[1][j]), fmaxf(s[2][j], s[3][j]));
      rm = fmaxf(rm, __shfl_xor(rm, 1));
      rm = fmaxf(rm, __shfl_xor(rm, 2));
      rm = fmaxf(rm, __shfl_xor(rm, 4));
      rm = fmaxf(rm, __shfl_xor(rm, 8));
      const float mnew = fmaxf(m_[j], rm);
      const float alpha = expf(m_[j] - mnew);
      float rs = 0.f;
#pragma unroll
      for (int f = 0; f < 4; f++) {
        const float p = expf(s[f][j] - mnew);
        s[f][j] = p;
        rs += p;
      }
      rs += __shfl_xor(rs, 1);
      rs += __shfl_xor(rs, 2);
      rs += __shfl_xor(rs, 4);
      rs += __shfl_xor(rs, 8);
      l_[j] = l_[j] * alpha + rs;
      m_[j] = mnew;
#pragma unroll
      for (int f = 0; f < 4; f++) accO[f][j] *= alpha;
    }

#pragma unroll
    for (int f = 0; f < 4; f++)
#pragma unroll
      for (int j = 0; j < 4; j++)
        Pb[wave][4 * hi + j][f * 16 + la] = f2bf(s[f][j]);

    short8 pf0 = *(const short8*)&Pb[wave][la][8 * hi];
    short8 pf1 = *(const short8*)&Pb[wave][la][32 + 8 * hi];
#pragma unroll
    for (int f = 0; f < 4; f++) {
      short8 vf0 = *(const short8*)&Vt[f * 16 + la][8 * hi];
      short8 vf1 = *(const short8*)&Vt[f * 16 + la][32 + 8 * hi];
      accO[f] = __builtin_amdgcn_mfma_f32_16x16x32_bf16(pf0, vf0, accO[f], 0, 0, 0);
      accO[f] = __builtin_amdgcn_mfma_f32_16x16x32_bf16(pf1, vf1, accO[f], 0, 0, 0);
    }
  }

  ushort* op = o + (size_t)(bb * SS + q0 + wave * 16) * DM + hh * HDIM;
#pragma unroll
  for (int j = 0; j < 4; j++) {
    const float inv = 1.0f / l_[j];
    const int qr = 4 * hi + j;
#pragma unroll
    for (int f = 0; f < 4; f++)
      op[(size_t)qr * DM + f * 16 + la] = f2bf(accO[f][j] * inv);
  }
}

// ================= legacy fallback (fp32 weights) ============
template <int EPI>
__global__ __launch_bounds__(256) void gemm_nt(const float* __restrict__ A,
    const float* __restrict__ Bw, const float* __restrict__ bias,
    const float* __restrict__ res, float* __restrict__ C, int N, int K) {
  __shared__ ushort As[64][40];
  __shared__ ushort Bs[64][40];
  const int tid = threadIdx.x;
  const int m0 = blockIdx.y * 64;
  const int n0 = blockIdx.x * 64;
  const int lane = tid & 63;
  const int wave = tid >> 6;
  const int wr = (wave >> 1) * 32;
  const int wc = (wave & 1) * 32;
  const int lr = lane & 15;
  const int lk = (lane >> 4) * 8;
  const int sr = tid >> 2;
  const int sc = (tid & 3) * 8;
  f32x4 acc[2][2] = {};
  for (int kk = 0; kk < K; kk += 32) {
    {
      const float* p = A + (size_t)(m0 + sr) * K + kk + sc;
      f32x4 v0 = *(const f32x4*)p;
      f32x4 v1 = *(const f32x4*)(p + 4);
      short8 sv;
      for (int i = 0; i < 4; i++) { sv[i] = f2bf(v0[i]); sv[4 + i] = f2bf(v1[i]); }
      *(short8*)&As[sr][sc] = sv;
    }
    {
      const int gr = n0 + sr;
      short8 sv = {};
      if (gr < N) {
        const float* p = Bw + (size_t)gr * K + kk + sc;
        f32x4 v0 = *(const f32x4*)p;
        f32x4 v1 = *(const f32x4*)(p + 4);
        for (int i = 0; i < 4; i++) { sv[i] = f2bf(v0[i]); sv[4 + i] = f2bf(v1[i]); }
      }
      *(short8*)&Bs[sr][sc] = sv;
    }
    __syncthreads();
    short8 a0 = *(const short8*)&As[wr + lr][lk];
    short8 a1 = *(const short8*)&As[wr + 16 + lr][lk];
    short8 b0 = *(const short8*)&Bs[wc + lr][lk];
    short8 b1 = *(const short8*)&Bs[wc + 16 + lr][lk];
    acc[0][0] = __builtin_amdgcn_mfma_f32_16x16x32_bf16(a0, b0, acc[0][0], 0, 0, 0);
    acc[0][1] = __builtin_amdgcn_mfma_f32_16x16x32_bf16(a0, b1, acc[0][1], 0, 0, 0);
    acc[1][0] = __builtin_amdgcn_mfma_f32_16x16x32_bf16(a1, b0, acc[1][0], 0, 0, 0);
    acc[1][1] = __builtin_amdgcn_mfma_f32_16x16x32_bf16(a1, b1, acc[1][1], 0, 0, 0);
    __syncthreads();
  }
  const int orow = (lane >> 4) * 4;
  for (int mi = 0; mi < 2; mi++)
    for (int ni = 0; ni < 2; ni++) {
      const int col = n0 + wc + ni * 16 + lr;
      if (col >= N) continue;
      for (int j = 0; j < 4; j++) {
        const int row = m0 + wr + mi * 16 + orow + j;
        float x = acc[mi][ni][j];
        if (EPI >= 1) x += bias[col];
        const size_t idx = (size_t)row * N + col;
        if (EPI == 2) x += res[idx];
        if (EPI == 3) x = 0.5f * x * (1.0f + erff(x * 0.70710678118f));
        C[idx] = x;
      }
    }
}

__global__ __launch_bounds__(256) void attn_f32(const float* __restrict__ qkv,
                                                float* __restrict__ o) {
  const int tid = threadIdx.x;
  const int lane = tid & 63;
  const int wave = tid >> 6;
  const int hi = lane >> 4;
  const int la = lane & 15;
  const int q0 = blockIdx.x * 64;
  const int bh = blockIdx.y;
  const int bb = bh / NH;
  const int hh = bh % NH;
  const size_t rstride = 3 * DM;
  const float* base = qkv + (size_t)bb * SS * rstride;
  __shared__ ushort Ks[64][72];
  __shared__ ushort Vt[64][72];
  __shared__ ushort Pb[4][16][72];
  short8 qf[2];
  {
    const int qrow = q0 + wave * 16 + la;
    const float* qp = base + (size_t)qrow * rstride + hh * HDIM + 8 * hi;
    for (int kk = 0; kk < 2; kk++) {
      f32x4 v0 = *(const f32x4*)(qp + 32 * kk);
      f32x4 v1 = *(const f32x4*)(qp + 32 * kk + 4);
      short8 sv;
      for (int i = 0; i < 4; i++) {
        sv[i] = f2bf(v0[i] * 0.125f); sv[4 + i] = f2bf(v1[i] * 0.125f);
      }
      qf[kk] = sv;
    }
  }
  f32x4 accO[4] = {};
  float m_[4], l_[4];
  for (int j = 0; j < 4; j++) { m_[j] = -1e30f; l_[j] = 0.f; }
  const int nt = q0 / 64 + 1;
  for (int kt = 0; kt < nt; kt++) {
    __syncthreads();
    {
      const int r = tid >> 2;
      const int c = (tid & 3) * 16;
      const float* kp = base + (size_t)(kt * 64 + r) * rstride + DM + hh * HDIM + c;
      const float* vp = kp + DM;
      f32x4 k0 = *(const f32x4*)kp, k1 = *(const f32x4*)(kp + 4);
      f32x4 k2 = *(const f32x4*)(kp + 8), k3 = *(const f32x4*)(kp + 12);
      short8 s0, s1;
      for (int i = 0; i < 4; i++) {
        s0[i] = f2bf(k0[i]); s0[4 + i] = f2bf(k1[i]);
        s1[i] = f2bf(k2[i]); s1[4 + i] = f2bf(k3[i]);
      }
      *(short8*)&Ks[r][c] = s0;
      *(short8*)&Ks[r][c + 8] = s1;
      f32x4 v0 = *(const f32x4*)vp, v1 = *(const f32x4*)(vp + 4);
      f32x4 v2 = *(const f32x4*)(vp + 8), v3 = *(const f32x4*)(vp + 12);
      for (int i = 0; i < 4; i++) {
        Vt[c + i][r] = f2bf(v0[i]); Vt[c + 4 + i][r] = f2bf(v1[i]);
        Vt[c + 8 + i][r] = f2bf(v2[i]); Vt[c + 12 + i][r] = f2bf(v3[i]);
      }
    }
    __syncthreads();
    f32x4 s[4] = {};
    for (int f = 0; f < 4; f++)
      for (int kk = 0; kk < 2; kk++) {
        short8 kf = *(const short8*)&Ks[f * 16 + la][kk * 32 + 8 * hi];
        s[f] = __builtin_amdgcn_mfma_f32_16x16x32_bf16(qf[kk], kf, s[f], 0, 0, 0);
      }
    if (kt == nt - 1) {
      const int qr = wave * 16 + 4 * hi;
      for (int f = 0; f < 4; f++) {
        const int kcol = f * 16 + la;
        for (int j = 0; j < 4; j++)
          if (kcol > qr + j) s[f][j] = -1e30f;
      }
    }
    for (int j = 0; j < 4; j++) {
      float rm = fmaxf(fmaxf(s[0][j], s[1][j]), fmaxf(s[2][j], s[3][j]));
      rm = fmaxf(rm, __shfl_xor(rm, 1));
      rm = fmaxf(rm, __shfl_xor(rm, 2));
      rm = fmaxf(rm, __shfl_xor(rm, 4));
      rm = fmaxf(rm, __shfl_xor(rm, 8));
      const float mnew = fmaxf(m_[j], rm);
      const float alpha = expf(m_[j] - mnew);
      float rs = 0.f;
      for (int f = 0; f < 4; f++) {
        const float p = expf(s[f][j] - mnew);
        s[f][j] = p; rs += p;
      }
      rs += __shfl_xor(rs, 1);
      rs += __shfl_xor(rs, 2);
      rs += __shfl_xor(rs, 4);
      rs += __shfl_xor(rs, 8);
      l_[j] = l_[j] * alpha + rs;
      m_[j] = mnew;
      for (int f = 0; f < 4; f++) accO[f][j] *= alpha;
    }
    for (int f = 0; f < 4; f++)
      for (int j = 0; j < 4; j++)
        Pb[wave][4 * hi + j][f * 16 + la] = f2bf(s[f][j]);
    short8 pf0 = *(const short8*)&Pb[wave][la][8 * hi];
    short8 pf1 = *(const short8*)&Pb[wave][la][32 + 8 * hi];
    for (int f = 0; f < 4; f++) {
      short8 vf0 = *(const short8*)&Vt[f * 16 + la][8 * hi];
      short8 vf1 = *(const short8*)&Vt[f * 16 + la][32 + 8 * hi];
      accO[f] = __builtin_amdgcn_mfma_f32_16x16x32_bf16(pf0, vf0, accO[f], 0, 0, 0);
      accO[f] = __builtin_amdgcn_mfma_f32_16x16x32_bf16(pf1, vf1, accO[f], 0, 0, 0);
    }
  }
  float* op = o + (size_t)(bb * SS + q0 + wave * 16) * DM + hh * HDIM;
  for (int j = 0; j < 4; j++) {
    const float inv = 1.0f / l_[j];
    const int qr = 4 * hi + j;
    for (int f = 0; f < 4; f++)
      op[(size_t)qr * DM + f * 16 + la] = accO[f][j] * inv;
  }
}

// ---------------- host launcher ----------------
extern "C" void kernel_launch(void* const* d_in, const int* in_sizes, int n_in,
                              void* d_out, int out_size, void* d_ws,
                              size_t ws_size, hipStream_t stream) {
  const int*   ids     = (const int*)d_in[0];
  const float* wte     = (const float*)d_in[1];
  const float* wpe     = (const float*)d_in[2];
  const float* ln1_g   = (const float*)d_in[3];
  const float* ln1_b   = (const float*)d_in[4];
  const float* qkv_w   = (const float*)d_in[5];
  const float* qkv_b   = (const float*)d_in[6];
  const float* proj_w  = (const float*)d_in[7];
  const float* proj_b  = (const float*)d_in[8];
  const float* ln2_g   = (const float*)d_in[9];
  const float* ln2_b   = (const float*)d_in[10];
  const float* fc_w    = (const float*)d_in[11];
  const float* fc_b    = (const float*)d_in[12];
  const float* cproj_w = (const float*)d_in[13];
  const float* cproj_b = (const float*)d_in[14];
  const float* lnf_g   = (const float*)d_in[15];
  const float* lnf_b   = (const float*)d_in[16];
  float* out = (float*)d_out;

  const size_t sz_h    = (size_t)ROWS * DM * 4;
  const size_t sz_hn   = (size_t)ROWS * DM * 2;
  const size_t sz_qkv  = (size_t)ROWS * 3 * DM * 2;
  const size_t sz_ob   = (size_t)ROWS * DM * 2;
  const size_t sz_mb   = (size_t)ROWS * DFFN * 2;
  const size_t sz_wq   = (size_t)NL * 3 * DM * DM * 2;
  const size_t sz_wp   = (size_t)NL * DM * DM * 2;
  const size_t sz_wf   = (size_t)NL * DFFN * DM * 2;
  const size_t sz_wc   = (size_t)NL * DM * DFFN * 2;
  const size_t sz_wt   = (size_t)VOC * DM * 2;
  const size_t NEED = sz_h + sz_hn + sz_qkv + sz_ob + sz_mb +
                      sz_wq + sz_wp + sz_wf + sz_wc + sz_wt;

  if (ws_size >= NEED) {
    char* p = (char*)d_ws;
    float*  h    = (float*)p;  p += sz_h;
    ushort* hn   = (ushort*)p; p += sz_hn;
    ushort* qkvb = (ushort*)p; p += sz_qkv;
    ushort* ob   = (ushort*)p; p += sz_ob;
    ushort* mb   = (ushort*)p; p += sz_mb;
    ushort* wq   = (ushort*)p; p += sz_wq;
    ushort* wp   = (ushort*)p; p += sz_wp;
    ushort* wf   = (ushort*)p; p += sz_wf;
    ushort* wc   = (ushort*)p; p += sz_wc;
    ushort* wt   = (ushort*)p; p += sz_wt;

    f2b_all<<<4096, 256, 0, stream>>>(qkv_w, proj_w, fc_w, cproj_w, wte,
                                      wq, wp, wf, wc, wt);
    embed_k<<<1536, 256, 0, stream>>>(ids, wte, wpe, h);

    for (int l = 0; l < NL; l++) {
      layernorm_t<1><<<ROWS / 4, 256, 0, stream>>>(h, ln1_g + l * DM, ln1_b + l * DM, hn);
      gemm_p3<1, 1, 4><<<MT * (3 * DM / 64), 256, 0, stream>>>(
          hn, wq + (size_t)l * 3 * DM * DM, qkv_b + (size_t)l * 3 * DM,
          nullptr, qkvb, 3 * DM, DM);
      attn_bf<<<dim3(SS / 64, BB * NH), 256, 0, stream>>>(qkvb, ob);
      gemm_p3<2, 0, 2><<<(ROWS / 64) * (DM / 64), 256, 0, stream>>>(
          ob, wp + (size_t)l * DM * DM, proj_b + (size_t)l * DM, h, h, DM, DM);
      layernorm_t<1><<<ROWS / 4, 256, 0, stream>>>(h, ln2_g + l * DM, ln2_b + l * DM, hn);
      gemm_p3<3, 1, 4><<<MT * (DFFN / 64), 256, 0, stream>>>(
          hn, wf + (size_t)l * DFFN * DM, fc_b + (size_t)l * DFFN,
          nullptr, mb, DFFN, DM);
      gemm_p3<2, 0, 2><<<(ROWS / 64) * (DM / 64), 256, 0, stream>>>(
          mb, wc + (size_t)l * DM * DFFN, cproj_b + (size_t)l * DM, h, h,
          DM, DFFN);
    }

    layernorm_t<1><<<ROWS / 4, 256, 0, stream>>>(h, lnf_g, lnf_b, hn);
    gemm_lg<<<MT * ((VOC + 127) / 128), 256, 0, stream>>>(
        hn, wt, out, VOC, DM);
  } else {
    float* ws = (float*)d_ws;
    float* h   = ws;
    float* hn  = h + (size_t)ROWS * DM;
    float* qkv = hn + (size_t)ROWS * DM;
    float* ob  = qkv + (size_t)ROWS * 3 * DM;
    float* mb  = ob + (size_t)ROWS * DM;

    embed_k<<<1536, 256, 0, stream>>>(ids, wte, wpe, h);
    for (int l = 0; l < NL; l++) {
      layernorm_t<0><<<ROWS / 4, 256, 0, stream>>>(h, ln1_g + l * DM, ln1_b + l * DM, hn);
      gemm_nt<1><<<dim3(3 * DM / 64, ROWS / 64), 256, 0, stream>>>(
          hn, qkv_w + (size_t)l * 3 * DM * DM, qkv_b + (size_t)l * 3 * DM,
          nullptr, qkv, 3 * DM, DM);
      attn_f32<<<dim3(SS / 64, BB * NH), 256, 0, stream>>>(qkv, ob);
      gemm_nt<2><<<dim3(DM / 64, ROWS / 64), 256, 0, stream>>>(
          ob, proj_w + (size_t)l * DM * DM, proj_b + (size_t)l * DM, h, h, DM, DM);
      layernorm_t<0><<<ROWS / 4, 256, 0, stream>>>(h, ln2_g + l * DM, ln2_b + l * DM, hn);
      gemm_nt<3><<<dim3(DFFN / 64, ROWS / 64), 256, 0, stream>>>(
          hn, fc_w + (size_t)l * DFFN * DM, fc_b + (size_t)l * DFFN,
          nullptr, mb, DFFN, DM);
      gemm_nt<2><<<dim3(DM / 64, ROWS / 64), 256, 0, stream>>>(
          mb, cproj_w + (size_t)l * DM * DFFN, cproj_b + (size_t)l * DM, h, h,
          DM, DFFN);
    }
    layernorm_t<0><<<ROWS / 4, 256, 0, stream>>>(h, lnf_g, lnf_b, hn);
    gemm_nt<0><<<dim3((VOC + 63) / 64, ROWS / 64), 256, 0, stream>>>(
        hn, wte, nullptr, nullptr, out, VOC, DM);
  }
}

// Round 14
// 1867.702 us; speedup vs baseline: 1.1095x; 1.0778x over previous
//
#include <hip/hip_runtime.h>

// GPT-2 small forward: B=2, S=1024, D=768, H=12, HD=64, L=12, DFF=3072, V=50257
#define BB 2
#define SS 1024
#define DM 768
#define NH 12
#define HDIM 64
#define NL 12
#define DFFN 3072
#define VOC 50257
#define ROWS (BB * SS)   // 2048
#define MT (ROWS / 128)  // 16 M-tiles for 128-row GEMMs

typedef __attribute__((ext_vector_type(4))) float f32x4;
typedef __attribute__((ext_vector_type(8))) short short8;
typedef __attribute__((ext_vector_type(4))) short short4v;
typedef unsigned short ushort;

__device__ __forceinline__ ushort f2bf(float f) {
  union { float f; unsigned int u; } x; x.f = f;
  unsigned int u = x.u;
  unsigned int r = (u + 0x7FFFu + ((u >> 16) & 1u)) >> 16;
  return (ushort)r;
}

// ---------------- embedding (vectorized f32x4 grid-stride) ----------------
__global__ __launch_bounds__(256) void embed_k(const int* __restrict__ ids,
    const float* __restrict__ wte, const float* __restrict__ wpe,
    float* __restrict__ h) {
  const int total = ROWS * (DM / 4);
  for (int i = blockIdx.x * 256 + threadIdx.x; i < total; i += gridDim.x * 256) {
    const int row = i / (DM / 4);
    const int col = i - row * (DM / 4);
    const int s = row & (SS - 1);
    const int id = ids[row];
    f32x4 w = ((const f32x4*)(wte + (size_t)id * DM))[col];
    f32x4 p = ((const f32x4*)(wpe + (size_t)s * DM))[col];
    ((f32x4*)(h + (size_t)row * DM))[col] = w + p;
  }
}

// ---------------- merged fp32 -> bf16 weight conversion ----------------
__global__ __launch_bounds__(256) void f2b_all(
    const float* __restrict__ s0, const float* __restrict__ s1,
    const float* __restrict__ s2, const float* __restrict__ s3,
    const float* __restrict__ s4, ushort* __restrict__ d0,
    ushort* __restrict__ d1, ushort* __restrict__ d2,
    ushort* __restrict__ d3, ushort* __restrict__ d4) {
  const int n0 = NL * 3 * DM * DM / 4;
  const int n1 = NL * DM * DM / 4;
  const int n2 = NL * DFFN * DM / 4;
  const int n3 = NL * DM * DFFN / 4;
  const int n4 = VOC * DM / 4;
  const int total = n0 + n1 + n2 + n3 + n4;
  for (int i = blockIdx.x * 256 + threadIdx.x; i < total; i += gridDim.x * 256) {
    const float* s; ushort* d; int j = i;
    if (j < n0) { s = s0; d = d0; }
    else { j -= n0;
      if (j < n1) { s = s1; d = d1; }
      else { j -= n1;
        if (j < n2) { s = s2; d = d2; }
        else { j -= n2;
          if (j < n3) { s = s3; d = d3; }
          else { j -= n3; s = s4; d = d4; }
        }
      }
    }
    f32x4 v = ((const f32x4*)s)[j];
    short4v o;
    o[0] = f2bf(v[0]); o[1] = f2bf(v[1]); o[2] = f2bf(v[2]); o[3] = f2bf(v[3]);
    ((short4v*)d)[j] = o;
  }
}

// legacy single-tensor convert (fallback path)
__global__ __launch_bounds__(256) void f2b_k(const float* __restrict__ in,
                                             ushort* __restrict__ out, int n4) {
  for (int i = blockIdx.x * 256 + threadIdx.x; i < n4; i += gridDim.x * 256) {
    f32x4 v = ((const f32x4*)in)[i];
    short4v s;
    s[0] = f2bf(v[0]); s[1] = f2bf(v[1]); s[2] = f2bf(v[2]); s[3] = f2bf(v[3]);
    ((short4v*)out)[i] = s;
  }
}

// ---------------- layernorm: one WAVE per row, shuffle-only ----------------
template <int OB>
__global__ __launch_bounds__(256) void layernorm_t(const float* __restrict__ x,
    const float* __restrict__ g, const float* __restrict__ b, void* __restrict__ y) {
  const int tid = threadIdx.x;
  const int lane = tid & 63;
  const int wave = tid >> 6;
  const int row = blockIdx.x * 4 + wave;
  const size_t base = (size_t)row * DM;

  f32x4 v[3];
  float sum = 0.f;
#pragma unroll
  for (int k = 0; k < 3; k++) {
    v[k] = *(const f32x4*)&x[base + k * 256 + lane * 4];
    sum += v[k][0] + v[k][1] + v[k][2] + v[k][3];
  }
#pragma unroll
  for (int off = 32; off >= 1; off >>= 1) sum += __shfl_xor(sum, off);
  const float mu = sum * (1.0f / DM);

  float var = 0.f;
#pragma unroll
  for (int k = 0; k < 3; k++)
#pragma unroll
    for (int i = 0; i < 4; i++) {
      const float d = v[k][i] - mu;
      var += d * d;
    }
#pragma unroll
  for (int off = 32; off >= 1; off >>= 1) var += __shfl_xor(var, off);
  const float rstd = rsqrtf(var * (1.0f / DM) + 1e-5f);

#pragma unroll
  for (int k = 0; k < 3; k++) {
    const int col = k * 256 + lane * 4;
    f32x4 gv = *(const f32x4*)&g[col];
    f32x4 bv = *(const f32x4*)&b[col];
    if (OB) {
      short4v o;
#pragma unroll
      for (int i = 0; i < 4; i++)
        o[i] = f2bf((v[k][i] - mu) * rstd * gv[i] + bv[i]);
      *(short4v*)&((ushort*)y)[base + col] = o;
    } else {
      f32x4 o;
#pragma unroll
      for (int i = 0; i < 4; i++)
        o[i] = (v[k][i] - mu) * rstd * gv[i] + bv[i];
      *(f32x4*)&((float*)y)[base + col] = o;
    }
  }
}

// -------- async stage (4 waves), T2 pre-swizzled source, linear LDS dest ---
template <int ROUNDS>
__device__ __forceinline__ void stage_sw(const ushort* __restrict__ g, int ldg,
                                         ushort* lds, int wave, int lane,
                                         int rowmax) {
#pragma unroll
  for (int r = 0; r < ROUNDS; r++) {
    const int chunk = (r * 4 + wave) * 64 + lane;
    const int nrow = chunk >> 3;
    const int cs = (chunk & 7) ^ (nrow & 7);
    const int row = nrow > rowmax ? rowmax : nrow;
    const ushort* ga = g + (size_t)row * ldg + cs * 8;
    ushort* la = lds + (r * 4 + wave) * 512;
    __builtin_amdgcn_global_load_lds(
        (const __attribute__((address_space(1))) unsigned int*)ga,
        (__attribute__((address_space(3))) unsigned int*)la, 16, 0, 0);
  }
}

// ---------------- logits GEMM: 128x128 tile, depth-1 counted vmcnt ---------
__global__ __launch_bounds__(256) void gemm_lg(const ushort* __restrict__ A,
    const ushort* __restrict__ Bw, float* __restrict__ Cout, int N, int K) {
  __shared__ __align__(16) ushort smem[4 * 8192];   // 64 KB
  ushort* AsL0 = smem;
  ushort* AsL1 = smem + 8192;
  ushort* BsL0 = smem + 16384;
  ushort* BsL1 = smem + 24576;

  const int tid = threadIdx.x;
  const int lane = tid & 63;
  const int wave = tid >> 6;
  const int la = lane & 15;
  const int hi = lane >> 4;
  const int swz = (la & 7) << 3;

  const int nwg = gridDim.x;
  int bid = blockIdx.x;
  {
    const int q = nwg >> 3, r = nwg & 7;
    const int xcd = bid & 7, idx = bid >> 3;
    bid = (xcd < r ? xcd * (q + 1) : r * (q + 1) + (xcd - r) * q) + idx;
  }
  const int m0 = (bid % MT) * 128;
  const int n0 = (bid / MT) * 128;

  const int wr = (wave >> 1) * 64;
  const int wc = (wave & 1) * 64;
  const int brmax = min(N - n0 - 1, 127);

  f32x4 acc[4][4];
#pragma unroll
  for (int i = 0; i < 4; i++)
#pragma unroll
    for (int j = 0; j < 4; j++) acc[i][j] = (f32x4){0.f, 0.f, 0.f, 0.f};

  const ushort* Ag = A + (size_t)m0 * K;
  const ushort* Bg = Bw + (size_t)n0 * K;

  const int nt = K >> 6;
  const int s0 = (bid % MT) % nt;

  stage_sw<4>(Ag + s0 * 64, K, AsL0, wave, lane, 127);
  stage_sw<4>(Bg + s0 * 64, K, BsL0, wave, lane, brmax);

  int cur = 0;
  for (int t = 0; t < nt; t++) {
    if (t + 1 < nt) {
      int sn = t + 1 + s0; if (sn >= nt) sn -= nt;
      stage_sw<4>(Ag + sn * 64, K, cur ? AsL0 : AsL1, wave, lane, 127);
      stage_sw<4>(Bg + sn * 64, K, cur ? BsL0 : BsL1, wave, lane, brmax);
      asm volatile("s_waitcnt vmcnt(8)" ::: "memory");
    } else {
      asm volatile("s_waitcnt vmcnt(0)" ::: "memory");
    }
    __builtin_amdgcn_s_barrier();
    __builtin_amdgcn_sched_barrier(0);

    const ushort* Ab = (cur ? AsL1 : AsL0) + (wr + la) * 64;
    const ushort* Bb = (cur ? BsL1 : BsL0) + (wc + la) * 64;
    __builtin_amdgcn_s_setprio(1);
#pragma unroll
    for (int ks = 0; ks < 2; ks++) {
      const int co = (ks * 32 + hi * 8) ^ swz;
      short8 a[4], b[4];
#pragma unroll
      for (int mi = 0; mi < 4; mi++)
        a[mi] = *(const short8*)(Ab + mi * 1024 + co);
#pragma unroll
      for (int ni = 0; ni < 4; ni++)
        b[ni] = *(const short8*)(Bb + ni * 1024 + co);
#pragma unroll
      for (int mi = 0; mi < 4; mi++)
#pragma unroll
        for (int ni = 0; ni < 4; ni++)
          acc[mi][ni] = __builtin_amdgcn_mfma_f32_16x16x32_bf16(
              a[mi], b[ni], acc[mi][ni], 0, 0, 0);
    }
    __builtin_amdgcn_s_setprio(0);
    __builtin_amdgcn_sched_barrier(0);
    __builtin_amdgcn_s_barrier();
    __builtin_amdgcn_sched_barrier(0);
    cur ^= 1;
  }

  // ---- two-half f32 LDS-transpose epilogue ----
  float* L = (float*)smem;   // [128][68]
  const int myhalf = wave & 1;
#pragma unroll
  for (int h = 0; h < 2; h++) {
    if (myhalf == h) {
#pragma unroll
      for (int mi = 0; mi < 4; mi++)
#pragma unroll
        for (int ni = 0; ni < 4; ni++)
#pragma unroll
          for (int j = 0; j < 4; j++) {
            const int row = wr + mi * 16 + 4 * hi + j;
            const int col = ni * 16 + la;
            L[row * 68 + col] = acc[mi][ni][j];
          }
    }
    __syncthreads();
#pragma unroll
    for (int it = 0; it < 32; it++) {
      const int flat = it * 256 + tid;
      const int row = flat >> 6, col = flat & 63;
      const int gc = n0 + h * 64 + col;
      if (gc < N)
        Cout[(size_t)(m0 + row) * N + gc] = L[row * 68 + col];
    }
    __syncthreads();
  }
}

// -------- layer GEMM: MROWS x 64 tile, 2-buffer depth-1, K-stagger ---------
// MR = MROWS/32. LDS = 2*(ASZ+BSZ): MR=4 -> 48 KB (3 blk/CU), MR=2 -> 32 KB.
template <int EPI, int OUTBF, int MR>
__global__ __launch_bounds__(256) void gemm_p3(const ushort* __restrict__ A,
    const ushort* __restrict__ Bw, const float* __restrict__ bias,
    const float* __restrict__ res, void* __restrict__ Cout, int N, int K) {
  constexpr int MROWS = MR * 32;
  constexpr int MTILES = ROWS / MROWS;
  constexpr int ASZ = MROWS * 64;
  constexpr int BSZ = 64 * 64;
  __shared__ __align__(16) ushort smem[2 * ASZ + 2 * BSZ];
  ushort* As = smem;
  ushort* Bs = smem + 2 * ASZ;

  const int tid = threadIdx.x;
  const int lane = tid & 63;
  const int wave = tid >> 6;
  const int la = lane & 15;
  const int hi = lane >> 4;
  const int swz = (la & 7) << 3;

  const int nwg = gridDim.x;
  int bid = blockIdx.x;
  {
    const int q = nwg >> 3, r = nwg & 7;
    const int xcd = bid & 7, idx = bid >> 3;
    bid = (xcd < r ? xcd * (q + 1) : r * (q + 1) + (xcd - r) * q) + idx;
  }
  const int m0 = (bid % MTILES) * MROWS;
  const int n0 = (bid / MTILES) * 64;

  const int wr = (wave >> 1) * (MROWS / 2);
  const int wc = (wave & 1) * 32;

  f32x4 acc[MR][2];
#pragma unroll
  for (int i = 0; i < MR; i++)
#pragma unroll
    for (int j = 0; j < 2; j++) acc[i][j] = (f32x4){0.f, 0.f, 0.f, 0.f};

  const ushort* Ag = A + (size_t)m0 * K;
  const ushort* Bg = Bw + (size_t)n0 * K;
  const int nt = K >> 6;
  const int s0 = (bid % MTILES) % nt;

  stage_sw<MR>(Ag + s0 * 64, K, As, wave, lane, MROWS - 1);
  stage_sw<2>(Bg + s0 * 64, K, Bs, wave, lane, 63);

  int cur = 0;
  for (int t = 0; t < nt; t++) {
    if (t + 1 < nt) {
      int sn = t + 1 + s0; if (sn >= nt) sn -= nt;
      stage_sw<MR>(Ag + sn * 64, K, As + (cur ^ 1) * ASZ, wave, lane, MROWS - 1);
      stage_sw<2>(Bg + sn * 64, K, Bs + (cur ^ 1) * BSZ, wave, lane, 63);
      asm volatile("s_waitcnt vmcnt(%0)" :: "i"(MR + 2) : "memory");
    } else {
      asm volatile("s_waitcnt vmcnt(0)" ::: "memory");
    }
    __builtin_amdgcn_s_barrier();
    __builtin_amdgcn_sched_barrier(0);

    const ushort* Ab = As + cur * ASZ + (wr + la) * 64;
    const ushort* Bb = Bs + cur * BSZ + (wc + la) * 64;
    __builtin_amdgcn_s_setprio(1);
#pragma unroll
    for (int ks = 0; ks < 2; ks++) {
      const int co = (ks * 32 + hi * 8) ^ swz;
      short8 a[MR], b[2];
#pragma unroll
      for (int mi = 0; mi < MR; mi++)
        a[mi] = *(const short8*)(Ab + mi * 1024 + co);
#pragma unroll
      for (int ni = 0; ni < 2; ni++)
        b[ni] = *(const short8*)(Bb + ni * 1024 + co);
#pragma unroll
      for (int mi = 0; mi < MR; mi++)
#pragma unroll
        for (int ni = 0; ni < 2; ni++)
          acc[mi][ni] = __builtin_amdgcn_mfma_f32_16x16x32_bf16(
              a[mi], b[ni], acc[mi][ni], 0, 0, 0);
    }
    __builtin_amdgcn_s_setprio(0);
    __builtin_amdgcn_sched_barrier(0);
    __builtin_amdgcn_s_barrier();
    __builtin_amdgcn_sched_barrier(0);
    cur ^= 1;
  }

  if (OUTBF) {
    ushort* L = smem;  // [MROWS][72]
#pragma unroll
    for (int mi = 0; mi < MR; mi++)
#pragma unroll
      for (int ni = 0; ni < 2; ni++)
#pragma unroll
        for (int j = 0; j < 4; j++) {
          const int row = wr + mi * 16 + 4 * hi + j;
          const int col = wc + ni * 16 + la;
          float x = acc[mi][ni][j];
          if (EPI >= 1) x += bias[n0 + col];
          if (EPI == 3) x = 0.5f * x * (1.0f + erff(x * 0.70710678118f));
          L[row * 72 + col] = f2bf(x);
        }
    __syncthreads();
    ushort* Co = (ushort*)Cout;
    constexpr int ITERS = MROWS * 64 / 8 / 256;
#pragma unroll
    for (int it = 0; it < ITERS; it++) {
      const int idx8 = it * 256 + tid;
      const int row = idx8 >> 3, c8 = idx8 & 7;
      short8 v = *(const short8*)&L[row * 72 + c8 * 8];
      *(short8*)&Co[(size_t)(m0 + row) * N + n0 + c8 * 8] = v;
    }
  } else {
    float* L = (float*)smem;  // [MROWS][68]
#pragma unroll
    for (int mi = 0; mi < MR; mi++)
#pragma unroll
      for (int ni = 0; ni < 2; ni++)
#pragma unroll
        for (int j = 0; j < 4; j++) {
          const int row = wr + mi * 16 + 4 * hi + j;
          const int col = wc + ni * 16 + la;
          float x = acc[mi][ni][j];
          if (EPI >= 1) x += bias[n0 + col];
          if (EPI == 3) x = 0.5f * x * (1.0f + erff(x * 0.70710678118f));
          L[row * 68 + col] = x;
        }
    __syncthreads();
    f32x4* Co = (f32x4*)Cout;
    const f32x4* R4 = (const f32x4*)res;
    constexpr int ITERS = MROWS * 64 / 4 / 256;
#pragma unroll
    for (int it = 0; it < ITERS; it++) {
      const int idx4 = it * 256 + tid;
      const int row = idx4 >> 4, c4 = idx4 & 15;
      f32x4 v = *(const f32x4*)&L[row * 68 + c4 * 4];
      const size_t o4 = ((size_t)(m0 + row) * N + n0) / 4 + c4;
      if (EPI == 2) v += R4[o4];
      Co[o4] = v;
    }
  }
}

// ---------------- flash attention, bf16 in/out, async reg staging ----------
__global__ __launch_bounds__(256) void attn_bf(const ushort* __restrict__ qkv,
                                               ushort* __restrict__ o) {
  const int tid = threadIdx.x;
  const int lane = tid & 63;
  const int wave = tid >> 6;
  const int hi = lane >> 4;
  const int la = lane & 15;
  const int q0 = blockIdx.x * 64;
  const int bh = blockIdx.y;
  const int bb = bh / NH;
  const int hh = bh % NH;
  const size_t rstride = 3 * DM;
  const ushort* base = qkv + (size_t)bb * SS * rstride;
  const ushort* kbase = base + DM + hh * HDIM;
  const ushort* vbase = base + 2 * DM + hh * HDIM;

  __shared__ ushort Ks[64][72];
  __shared__ ushort Vt[64][72];
  __shared__ ushort Pb[4][16][72];

  const int kr = tid >> 2;
  const int kc = (tid & 3) * 16;
  const int vp0 = (tid >> 3) * 2;
  const int vc = (tid & 7) * 8;

  short8 qf[2];
  {
    const int qrow = q0 + wave * 16 + la;
    const ushort* qp = base + (size_t)qrow * rstride + hh * HDIM + 8 * hi;
    qf[0] = *(const short8*)qp;
    qf[1] = *(const short8*)(qp + 32);
  }

  short8 kA, kB, vA, vB;
  {
    const ushort* kp = kbase + (size_t)kr * rstride + kc;
    kA = *(const short8*)kp;
    kB = *(const short8*)(kp + 8);
    const ushort* vp = vbase + (size_t)vp0 * rstride + vc;
    vA = *(const short8*)vp;
    vB = *(const short8*)(vp + rstride);
  }

  f32x4 accO[4] = {};
  float m_[4], l_[4];
#pragma unroll
  for (int j = 0; j < 4; j++) { m_[j] = -1e30f; l_[j] = 0.f; }

  const int nt = q0 / 64 + 1;
  for (int kt = 0; kt < nt; kt++) {
    __syncthreads();
    *(short8*)&Ks[kr][kc]     = kA;
    *(short8*)&Ks[kr][kc + 8] = kB;
#pragma unroll
    for (int i = 0; i < 8; i++) {
      unsigned int pk = (unsigned int)(unsigned short)vA[i] |
                        ((unsigned int)(unsigned short)vB[i] << 16);
      *(unsigned int*)&Vt[vc + i][vp0] = pk;
    }
    __syncthreads();
    if (kt + 1 < nt) {
      const ushort* kp = kbase + (size_t)((kt + 1) * 64 + kr) * rstride + kc;
      kA = *(const short8*)kp;
      kB = *(const short8*)(kp + 8);
      const ushort* vp = vbase + (size_t)((kt + 1) * 64 + vp0) * rstride + vc;
      vA = *(const short8*)vp;
      vB = *(const short8*)(vp + rstride);
    }

    f32x4 s[4] = {};
#pragma unroll
    for (int f = 0; f < 4; f++) {
#pragma unroll
      for (int kk = 0; kk < 2; kk++) {
        short8 kf = *(const short8*)&Ks[f * 16 + la][kk * 32 + 8 * hi];
        s[f] = __builtin_amdgcn_mfma_f32_16x16x32_bf16(qf[kk], kf, s[f], 0, 0, 0);
      }
#pragma unroll
      for (int j = 0; j < 4; j++) s[f][j] *= 0.125f;
    }

    if (kt == nt - 1) {
      const int qr = wave * 16 + 4 * hi;
#pragma unroll
      for (int f = 0; f < 4; f++) {
        const int kcol = f * 16 + la;
#pragma unroll
        for (int j = 0; j < 4; j++)
          if (kcol > qr + j) s[f][j] = -1e30f;
      }
    }

#pragma unroll
    for (int j = 0; j < 4; j++) {
      float rm = fmaxf(fmaxf(s[0][j], s[1][j]), fmaxf(s[2][j], s[3][j]));
      rm = fmaxf(rm, __shfl_xor(rm, 1));
      rm = fmaxf(rm, __shfl_xor(rm, 2));
      rm = fmaxf(rm, __shfl_xor(rm, 4));
      rm = fmaxf(rm, __shfl_xor(rm, 8));
      const float mnew = fmaxf(m_[j], rm);
      const float alpha = expf(m_[j] - mnew);
      float rs = 0.f;
#pragma unroll
      for (int f = 0; f < 4; f++) {
        const float p = expf(s[f][j] - mnew);
        s[f][j] = p;
        rs += p;
      }
      rs += __shfl_xor(rs, 1);
      rs += __shfl_xor(rs, 2);
      rs += __shfl_xor(rs, 4);
      rs += __shfl_xor(rs, 8);
      l_[j] = l_[j] * alpha + rs;
      m_[j] = mnew;
#pragma unroll
      for (int f = 0; f < 4; f++) accO[f][j] *= alpha;
    }

#pragma unroll
    for (int f = 0; f < 4; f++)
#pragma unroll
      for (int j = 0; j < 4; j++)
        Pb[wave][4 * hi + j][f * 16 + la] = f2bf(s[f][j]);

    short8 pf0 = *(const short8*)&Pb[wave][la][8 * hi];
    short8 pf1 = *(const short8*)&Pb[wave][la][32 + 8 * hi];
#pragma unroll
    for (int f = 0; f < 4; f++) {
      short8 vf0 = *(const short8*)&Vt[f * 16 + la][8 * hi];
      short8 vf1 = *(const short8*)&Vt[f * 16 + la][32 + 8 * hi];
      accO[f] = __builtin_amdgcn_mfma_f32_16x16x32_bf16(pf0, vf0, accO[f], 0, 0, 0);
      accO[f] = __builtin_amdgcn_mfma_f32_16x16x32_bf16(pf1, vf1, accO[f], 0, 0, 0);
    }
  }

  ushort* op = o + (size_t)(bb * SS + q0 + wave * 16) * DM + hh * HDIM;
#pragma unroll
  for (int j = 0; j < 4; j++) {
    const float inv = 1.0f / l_[j];
    const int qr = 4 * hi + j;
#pragma unroll
    for (int f = 0; f < 4; f++)
      op[(size_t)qr * DM + f * 16 + la] = f2bf(accO[f][j] * inv);
  }
}

// ================= legacy fallback (fp32 weights) ============
template <int EPI>
__global__ __launch_bounds__(256) void gemm_nt(const float* __restrict__ A,
    const float* __restrict__ Bw, const float* __restrict__ bias,
    const float* __restrict__ res, float* __restrict__ C, int N, int K) {
  __shared__ ushort As[64][40];
  __shared__ ushort Bs[64][40];
  const int tid = threadIdx.x;
  const int m0 = blockIdx.y * 64;
  const int n0 = blockIdx.x * 64;
  const int lane = tid & 63;
  const int wave = tid >> 6;
  const int wr = (wave >> 1) * 32;
  const int wc = (wave & 1) * 32;
  const int lr = lane & 15;
  const int lk = (lane >> 4) * 8;
  const int sr = tid >> 2;
  const int sc = (tid & 3) * 8;
  f32x4 acc[2][2] = {};
  for (int kk = 0; kk < K; kk += 32) {
    {
      const float* p = A + (size_t)(m0 + sr) * K + kk + sc;
      f32x4 v0 = *(const f32x4*)p;
      f32x4 v1 = *(const f32x4*)(p + 4);
      short8 sv;
      for (int i = 0; i < 4; i++) { sv[i] = f2bf(v0[i]); sv[4 + i] = f2bf(v1[i]); }
      *(short8*)&As[sr][sc] = sv;
    }
    {
      const int gr = n0 + sr;
      short8 sv = {};
      if (gr < N) {
        const float* p = Bw + (size_t)gr * K + kk + sc;
        f32x4 v0 = *(const f32x4*)p;
        f32x4 v1 = *(const f32x4*)(p + 4);
        for (int i = 0; i < 4; i++) { sv[i] = f2bf(v0[i]); sv[4 + i] = f2bf(v1[i]); }
      }
      *(short8*)&Bs[sr][sc] = sv;
    }
    __syncthreads();
    short8 a0 = *(const short8*)&As[wr + lr][lk];
    short8 a1 = *(const short8*)&As[wr + 16 + lr][lk];
    short8 b0 = *(const short8*)&Bs[wc + lr][lk];
    short8 b1 = *(const short8*)&Bs[wc + 16 + lr][lk];
    acc[0][0] = __builtin_amdgcn_mfma_f32_16x16x32_bf16(a0, b0, acc[0][0], 0, 0, 0);
    acc[0][1] = __builtin_amdgcn_mfma_f32_16x16x32_bf16(a0, b1, acc[0][1], 0, 0, 0);
    acc[1][0] = __builtin_amdgcn_mfma_f32_16x16x32_bf16(a1, b0, acc[1][0], 0, 0, 0);
    acc[1][1] = __builtin_amdgcn_mfma_f32_16x16x32_bf16(a1, b1, acc[1][1], 0, 0, 0);
    __syncthreads();
  }
  const int orow = (lane >> 4) * 4;
  for (int mi = 0; mi < 2; mi++)
    for (int ni = 0; ni < 2; ni++) {
      const int col = n0 + wc + ni * 16 + lr;
      if (col >= N) continue;
      for (int j = 0; j < 4; j++) {
        const int row = m0 + wr + mi * 16 + orow + j;
        float x = acc[mi][ni][j];
        if (EPI >= 1) x += bias[col];
        const size_t idx = (size_t)row * N + col;
        if (EPI == 2) x += res[idx];
        if (EPI == 3) x = 0.5f * x * (1.0f + erff(x * 0.70710678118f));
        C[idx] = x;
      }
    }
}

__global__ __launch_bounds__(256) void attn_f32(const float* __restrict__ qkv,
                                                float* __restrict__ o) {
  const int tid = threadIdx.x;
  const int lane = tid & 63;
  const int wave = tid >> 6;
  const int hi = lane >> 4;
  const int la = lane & 15;
  const int q0 = blockIdx.x * 64;
  const int bh = blockIdx.y;
  const int bb = bh / NH;
  const int hh = bh % NH;
  const size_t rstride = 3 * DM;
  const float* base = qkv + (size_t)bb * SS * rstride;
  __shared__ ushort Ks[64][72];
  __shared__ ushort Vt[64][72];
  __shared__ ushort Pb[4][16][72];
  short8 qf[2];
  {
    const int qrow = q0 + wave * 16 + la;
    const float* qp = base + (size_t)qrow * rstride + hh * HDIM + 8 * hi;
    for (int kk = 0; kk < 2; kk++) {
      f32x4 v0 = *(const f32x4*)(qp + 32 * kk);
      f32x4 v1 = *(const f32x4*)(qp + 32 * kk + 4);
      short8 sv;
      for (int i = 0; i < 4; i++) {
        sv[i] = f2bf(v0[i] * 0.125f); sv[4 + i] = f2bf(v1[i] * 0.125f);
      }
      qf[kk] = sv;
    }
  }
  f32x4 accO[4] = {};
  float m_[4], l_[4];
  for (int j = 0; j < 4; j++) { m_[j] = -1e30f; l_[j] = 0.f; }
  const int nt = q0 / 64 + 1;
  for (int kt = 0; kt < nt; kt++) {
    __syncthreads();
    {
      const int r = tid >> 2;
      const int c = (tid & 3) * 16;
      const float* kp = base + (size_t)(kt * 64 + r) * rstride + DM + hh * HDIM + c;
      const float* vp = kp + DM;
      f32x4 k0 = *(const f32x4*)kp, k1 = *(const f32x4*)(kp + 4);
      f32x4 k2 = *(const f32x4*)(kp + 8), k3 = *(const f32x4*)(kp + 12);
      short8 s0, s1;
      for (int i = 0; i < 4; i++) {
        s0[i] = f2bf(k0[i]); s0[4 + i] = f2bf(k1[i]);
        s1[i] = f2bf(k2[i]); s1[4 + i] = f2bf(k3[i]);
      }
      *(short8*)&Ks[r][c] = s0;
      *(short8*)&Ks[r][c + 8] = s1;
      f32x4 v0 = *(const f32x4*)vp, v1 = *(const f32x4*)(vp + 4);
      f32x4 v2 = *(const f32x4*)(vp + 8), v3 = *(const f32x4*)(vp + 12);
      for (int i = 0; i < 4; i++) {
        Vt[c + i][r] = f2bf(v0[i]); Vt[c + 4 + i][r] = f2bf(v1[i]);
        Vt[c + 8 + i][r] = f2bf(v2[i]); Vt[c + 12 + i][r] = f2bf(v3[i]);
      }
    }
    __syncthreads();
    f32x4 s[4] = {};
    for (int f = 0; f < 4; f++)
      for (int kk = 0; kk < 2; kk++) {
        short8 kf = *(const short8*)&Ks[f * 16 + la][kk * 32 + 8 * hi];
        s[f] = __builtin_amdgcn_mfma_f32_16x16x32_bf16(qf[kk], kf, s[f], 0, 0, 0);
      }
    if (kt == nt - 1) {
      const int qr = wave * 16 + 4 * hi;
      for (int f = 0; f < 4; f++) {
        const int kcol = f * 16 + la;
        for (int j = 0; j < 4; j++)
          if (kcol > qr + j) s[f][j] = -1e30f;
      }
    }
    for (int j = 0; j < 4; j++) {
      float rm = fmaxf(fmaxf(s[0][j], s[1][j]), fmaxf(s[2][j], s[3][j]));
      rm = fmaxf(rm, __shfl_xor(rm, 1));
      rm = fmaxf(rm, __shfl_xor(rm, 2));
      rm = fmaxf(rm, __shfl_xor(rm, 4));
      rm = fmaxf(rm, __shfl_xor(rm, 8));
      const float mnew = fmaxf(m_[j], rm);
      const float alpha = expf(m_[j] - mnew);
      float rs = 0.f;
      for (int f = 0; f < 4; f++) {
        const float p = expf(s[f][j] - mnew);
        s[f][j] = p; rs += p;
      }
      rs += __shfl_xor(rs, 1);
      rs += __shfl_xor(rs, 2);
      rs += __shfl_xor(rs, 4);
      rs += __shfl_xor(rs, 8);
      l_[j] = l_[j] * alpha + rs;
      m_[j] = mnew;
      for (int f = 0; f < 4; f++) accO[f][j] *= alpha;
    }
    for (int f = 0; f < 4; f++)
      for (int j = 0; j < 4; j++)
        Pb[wave][4 * hi + j][f * 16 + la] = f2bf(s[f][j]);
    short8 pf0 = *(const short8*)&Pb[wave][la][8 * hi];
    short8 pf1 = *(const short8*)&Pb[wave][la][32 + 8 * hi];
    for (int f = 0; f < 4; f++) {
      short8 vf0 = *(const short8*)&Vt[f * 16 + la][8 * hi];
      short8 vf1 = *(const short8*)&Vt[f * 16 + la][32 + 8 * hi];
      accO[f] = __builtin_amdgcn_mfma_f32_16x16x32_bf16(pf0, vf0, accO[f], 0, 0, 0);
      accO[f] = __builtin_amdgcn_mfma_f32_16x16x32_bf16(pf1, vf1, accO[f], 0, 0, 0);
    }
  }
  float* op = o + (size_t)(bb * SS + q0 + wave * 16) * DM + hh * HDIM;
  for (int j = 0; j < 4; j++) {
    const float inv = 1.0f / l_[j];
    const int qr = 4 * hi + j;
    for (int f = 0; f < 4; f++)
      op[(size_t)qr * DM + f * 16 + la] = accO[f][j] * inv;
  }
}

// ---------------- host launcher ----------------
extern "C" void kernel_launch(void* const* d_in, const int* in_sizes, int n_in,
                              void* d_out, int out_size, void* d_ws,
                              size_t ws_size, hipStream_t stream) {
  const int*   ids     = (const int*)d_in[0];
  const float* wte     = (const float*)d_in[1];
  const float* wpe     = (const float*)d_in[2];
  const float* ln1_g   = (const float*)d_in[3];
  const float* ln1_b   = (const float*)d_in[4];
  const float* qkv_w   = (const float*)d_in[5];
  const float* qkv_b   = (const float*)d_in[6];
  const float* proj_w  = (const float*)d_in[7];
  const float* proj_b  = (const float*)d_in[8];
  const float* ln2_g   = (const float*)d_in[9];
  const float* ln2_b   = (const float*)d_in[10];
  const float* fc_w    = (const float*)d_in[11];
  const float* fc_b    = (const float*)d_in[12];
  const float* cproj_w = (const float*)d_in[13];
  const float* cproj_b = (const float*)d_in[14];
  const float* lnf_g   = (const float*)d_in[15];
  const float* lnf_b   = (const float*)d_in[16];
  float* out = (float*)d_out;

  const size_t sz_h    = (size_t)ROWS * DM * 4;
  const size_t sz_hn   = (size_t)ROWS * DM * 2;
  const size_t sz_qkv  = (size_t)ROWS * 3 * DM * 2;
  const size_t sz_ob   = (size_t)ROWS * DM * 2;
  const size_t sz_mb   = (size_t)ROWS * DFFN * 2;
  const size_t sz_wq   = (size_t)NL * 3 * DM * DM * 2;
  const size_t sz_wp   = (size_t)NL * DM * DM * 2;
  const size_t sz_wf   = (size_t)NL * DFFN * DM * 2;
  const size_t sz_wc   = (size_t)NL * DM * DFFN * 2;
  const size_t sz_wt   = (size_t)VOC * DM * 2;
  const size_t NEED = sz_h + sz_hn + sz_qkv + sz_ob + sz_mb +
                      sz_wq + sz_wp + sz_wf + sz_wc + sz_wt;

  if (ws_size >= NEED) {
    char* p = (char*)d_ws;
    float*  h    = (float*)p;  p += sz_h;
    ushort* hn   = (ushort*)p; p += sz_hn;
    ushort* qkvb = (ushort*)p; p += sz_qkv;
    ushort* ob   = (ushort*)p; p += sz_ob;
    ushort* mb   = (ushort*)p; p += sz_mb;
    ushort* wq   = (ushort*)p; p += sz_wq;
    ushort* wp   = (ushort*)p; p += sz_wp;
    ushort* wf   = (ushort*)p; p += sz_wf;
    ushort* wc   = (ushort*)p; p += sz_wc;
    ushort* wt   = (ushort*)p; p += sz_wt;

    f2b_all<<<4096, 256, 0, stream>>>(qkv_w, proj_w, fc_w, cproj_w, wte,
                                      wq, wp, wf, wc, wt);
    embed_k<<<1536, 256, 0, stream>>>(ids, wte, wpe, h);

    for (int l = 0; l < NL; l++) {
      layernorm_t<1><<<ROWS / 4, 256, 0, stream>>>(h, ln1_g + l * DM, ln1_b + l * DM, hn);
      gemm_p3<1, 1, 4><<<MT * (3 * DM / 64), 256, 0, stream>>>(
          hn, wq + (size_t)l * 3 * DM * DM, qkv_b + (size_t)l * 3 * DM,
          nullptr, qkvb, 3 * DM, DM);
      attn_bf<<<dim3(SS / 64, BB * NH), 256, 0, stream>>>(qkvb, ob);
      gemm_p3<2, 0, 2><<<(ROWS / 64) * (DM / 64), 256, 0, stream>>>(
          ob, wp + (size_t)l * DM * DM, proj_b + (size_t)l * DM, h, h, DM, DM);
      layernorm_t<1><<<ROWS / 4, 256, 0, stream>>>(h, ln2_g + l * DM, ln2_b + l * DM, hn);
      gemm_p3<3, 1, 4><<<MT * (DFFN / 64), 256, 0, stream>>>(
          hn, wf + (size_t)l * DFFN * DM, fc_b + (size_t)l * DFFN,
          nullptr, mb, DFFN, DM);
      gemm_p3<2, 0, 2><<<(ROWS / 64) * (DM / 64), 256, 0, stream>>>(
          mb, wc + (size_t)l * DM * DFFN, cproj_b + (size_t)l * DM, h, h,
          DM, DFFN);
    }

    layernorm_t<1><<<ROWS / 4, 256, 0, stream>>>(h, lnf_g, lnf_b, hn);
    gemm_lg<<<MT * ((VOC + 127) / 128), 256, 0, stream>>>(
        hn, wt, out, VOC, DM);
  } else {
    float* ws = (float*)d_ws;
    float* h   = ws;
    float* hn  = h + (size_t)ROWS * DM;
    float* qkv = hn + (size_t)ROWS * DM;
    float* ob  = qkv + (size_t)ROWS * 3 * DM;
    float* mb  = ob + (size_t)ROWS * DM;

    embed_k<<<1536, 256, 0, stream>>>(ids, wte, wpe, h);
    for (int l = 0; l < NL; l++) {
      layernorm_t<0><<<ROWS / 4, 256, 0, stream>>>(h, ln1_g + l * DM, ln1_b + l * DM, hn);
      gemm_nt<1><<<dim3(3 * DM / 64, ROWS / 64), 256, 0, stream>>>(
          hn, qkv_w + (size_t)l * 3 * DM * DM, qkv_b + (size_t)l * 3 * DM,
          nullptr, qkv, 3 * DM, DM);
      attn_f32<<<dim3(SS / 64, BB * NH), 256, 0, stream>>>(qkv, ob);
      gemm_nt<2><<<dim3(DM / 64, ROWS / 64), 256, 0, stream>>>(
          ob, proj_w + (size_t)l * DM * DM, proj_b + (size_t)l * DM, h, h, DM, DM);
      layernorm_t<0><<<ROWS / 4, 256, 0, stream>>>(h, ln2_g + l * DM, ln2_b + l * DM, hn);
      gemm_nt<3><<<dim3(DFFN / 64, ROWS / 64), 256, 0, stream>>>(
          hn, fc_w + (size_t)l * DFFN * DM, fc_b + (size_t)l * DFFN,
          nullptr, mb, DFFN, DM);
      gemm_nt<2><<<dim3(DM / 64, ROWS / 64), 256, 0, stream>>>(
          mb, cproj_w + (size_t)l * DM * DFFN, cproj_b + (size_t)l * DM, h, h,
          DM, DFFN);
    }
    layernorm_t<0><<<ROWS / 4, 256, 0, stream>>>(h, lnf_g, lnf_b, hn);
    gemm_nt<0><<<dim3((VOC + 63) / 64, ROWS / 64), 256, 0, stream>>>(
        hn, wte, nullptr, nullptr, out, VOC, DM);
  }
}